// Round 3
// baseline (264.276 us; speedup 1.0000x reference)
//
#include <hip/hip_runtime.h>

typedef __bf16 bf16_t;
typedef __bf16 bf16x8 __attribute__((ext_vector_type(8)));
typedef __bf16 bf16x4 __attribute__((ext_vector_type(4)));
typedef float  floatx4 __attribute__((ext_vector_type(4)));

#define BM 128
#define BN 128
#define BK 64

// async global->LDS, 16B per lane. LDS dest is wave-uniform base + lane*16 (no
// scatter, no padding) — conflict-avoidance is done by permuting the GLOBAL
// chunk each lane fetches (XOR swizzle), not the LDS address.
__device__ __forceinline__ void gld_lds16(const bf16_t* g, bf16_t* l) {
  __builtin_amdgcn_global_load_lds(
      (__attribute__((address_space(1))) const void*)g,
      (__attribute__((address_space(3))) void*)l, 16, 0, 0);
}

// 64x128 variant: BM=64, BN=128, waves 2x2 each 32x64, acc[2][4].
// LDS row-major [rows][BK=64]; chunk s of row r holds global chunk s^(r&7).
__device__ __forceinline__ void gemm_bt_core64(
    const bf16_t* __restrict__ A, int lda,
    const bf16_t* __restrict__ Bt, int ldb,
    int rowBase, int colBase, int kTiles,
    bf16_t* ldsA, bf16_t* ldsB, floatx4 acc[2][4])
{
  const int t    = threadIdx.x;
  const int lane = t & 63;
  const int wave = t >> 6;
  const int wy   = wave >> 1;      // 32-row half
  const int wx   = wave & 1;       // 64-col half
  const int quad = lane >> 4;
  const int r16  = lane & 15;

  const int srow   = t >> 3;
  const int schunk = (t & 7) ^ (srow & 7);
  const bf16_t* ga = A  + (size_t)(rowBase + srow) * lda + schunk * 8;
  const bf16_t* gb = Bt + (size_t)(colBase + srow) * ldb + schunk * 8;
  bf16_t* la = ldsA + t * 8;
  bf16_t* lb = ldsB + t * 8;

#pragma unroll
  for (int i = 0; i < 2; ++i)
#pragma unroll
    for (int j = 0; j < 4; ++j)
      acc[i][j] = (floatx4){0.f, 0.f, 0.f, 0.f};

  for (int kt = 0; kt < kTiles; ++kt) {
    const int k0 = kt * BK;
    gld_lds16(ga + k0,                    la);             // A: 64 rows = 2 issues
    gld_lds16(ga + k0 + (size_t)32 * lda, la + 32 * BK);
#pragma unroll
    for (int is = 0; is < 4; ++is)                         // B: 128 rows = 4 issues
      gld_lds16(gb + k0 + (size_t)(32 * is) * ldb, lb + is * (32 * BK));
    __syncthreads();

#pragma unroll
    for (int h = 0; h < 2; ++h) {
      bf16x8 af[2], bfr[4];
#pragma unroll
      for (int i = 0; i < 2; ++i) {
        const int r = wy * 32 + i * 16 + r16;
        af[i] = *(const bf16x8*)(ldsA + r * BK + (((h << 2) + quad) ^ (r16 & 7)) * 8);
      }
#pragma unroll
      for (int j = 0; j < 4; ++j) {
        const int r = wx * 64 + j * 16 + r16;
        bfr[j] = *(const bf16x8*)(ldsB + r * BK + (((h << 2) + quad) ^ (r16 & 7)) * 8);
      }
#pragma unroll
      for (int i = 0; i < 2; ++i)
#pragma unroll
        for (int j = 0; j < 4; ++j)
          acc[i][j] = __builtin_amdgcn_mfma_f32_16x16x32_bf16(af[i], bfr[j], acc[i][j], 0, 0, 0);
    }
    __syncthreads();
  }
}

#define EPILOGUE_SETUP()                       \
  const int t    = threadIdx.x;                \
  const int lane = t & 63;                     \
  const int wave = t >> 6;                     \
  const int wy   = wave >> 1;                  \
  const int wx   = wave & 1;                   \
  const int quad = lane >> 4;                  \
  const int r16  = lane & 15;

// ---------------- fused prep kernel ----------------
// blocks [0,4096): x fp32 -> bf16, 8 elems/thread; blocks [0,32) also zero rowsum
// blocks [4096,7168): transpose+cvt w_qkv [1024,3072] -> [3072,1024]
// blocks [7168,8192): transpose+cvt w_out [1024,1024] -> [1024,1024]
// blocks [8192,8704): strided cvt w_qkv[:,2048:3072] -> wvb[1024,1024] bf16
//                     (row-major Wv, no transpose — feeds k_wcomb's Bt)
__global__ void __launch_bounds__(256) k_prep(
    const float* __restrict__ x, bf16_t* __restrict__ xb,
    const float* __restrict__ w_qkv, bf16_t* __restrict__ wqt,
    const float* __restrict__ w_out, bf16_t* __restrict__ wot,
    float* __restrict__ rowsum, bf16_t* __restrict__ wvb) {
  __shared__ float tile[32][33];
  const int bxk = blockIdx.x;
  const int t = threadIdx.x;
  if (bxk < 4096) {
    const size_t idx = (size_t)bxk * 256 + t;
    if (bxk < 32) rowsum[idx] = 0.0f;
    const float4 v0 = ((const float4*)x)[idx * 2];
    const float4 v1 = ((const float4*)x)[idx * 2 + 1];
    bf16x8 o;
    o[0] = (bf16_t)v0.x; o[1] = (bf16_t)v0.y; o[2] = (bf16_t)v0.z; o[3] = (bf16_t)v0.w;
    o[4] = (bf16_t)v1.x; o[5] = (bf16_t)v1.y; o[6] = (bf16_t)v1.z; o[7] = (bf16_t)v1.w;
    ((bf16x8*)xb)[idx] = o;
    return;
  }
  if (bxk >= 8192) {
    const int tb = bxk - 8192;
    const size_t idx = (size_t)tb * 2048 + (size_t)t * 8;   // idx = d*1024 + e
    const int d = (int)(idx >> 10);
    const int e = (int)(idx & 1023);
    const float* src = w_qkv + (size_t)d * 3072 + 2048 + e;
    const float4 v0 = *(const float4*)src;
    const float4 v1 = *(const float4*)(src + 4);
    bf16x8 o;
    o[0] = (bf16_t)v0.x; o[1] = (bf16_t)v0.y; o[2] = (bf16_t)v0.z; o[3] = (bf16_t)v0.w;
    o[4] = (bf16_t)v1.x; o[5] = (bf16_t)v1.y; o[6] = (bf16_t)v1.z; o[7] = (bf16_t)v1.w;
    *(bf16x8*)(wvb + idx) = o;
    return;
  }
  const bool first = bxk < 7168;
  const int tb = first ? (bxk - 4096) : (bxk - 7168);
  const float* in = first ? w_qkv : w_out;
  bf16_t* out = first ? wqt : wot;
  const int C = first ? 3072 : 1024;
  const int nCB = C >> 5;
  const int c0 = (tb % nCB) * 32;
  const int r0 = (tb / nCB) * 32;
  const int tx = t & 31, ty = t >> 5;
#pragma unroll
  for (int rr = 0; rr < 32; rr += 8)
    tile[ty + rr][tx] = in[(size_t)(r0 + ty + rr) * C + (c0 + tx)];
  __syncthreads();
#pragma unroll
  for (int cc = 0; cc < 32; cc += 8)
    out[(size_t)(c0 + ty + cc) * 1024 + (r0 + tx)] = (bf16_t)tile[tx][ty + cc];
}

// ---------------- GEMM kernels ----------------

// WCOMB: wcombt[n,d] = sum_e wot[n,e] * wvb[d,e] = (Wv @ Wout)^T.
// 2.1 GFLOP on 128 blocks — replaces the 17.2-GFLOP VW GEMM because
// V is only ever consumed as V@Wout: X@(Wv@Wout) == (X@Wv)@Wout.
__global__ void __launch_bounds__(256) k_wcomb(
    const bf16_t* __restrict__ wot, const bf16_t* __restrict__ wvb,
    bf16_t* __restrict__ wcombt) {
  __shared__ bf16_t ldsA[64 * BK];
  __shared__ bf16_t ldsB[BN * BK];
  floatx4 acc[2][4];
  const int l = blockIdx.x;
  const int by = l >> 3, bx = l & 7;
  const int rowBase = by * 64, colBase = bx * BN;
  gemm_bt_core64(wot, 1024, wvb, 1024, rowBase, colBase, 1024 / BK, ldsA, ldsB, acc);
  EPILOGUE_SETUP();
#pragma unroll
  for (int i = 0; i < 2; ++i) {
    const int m0 = rowBase + wy * 32 + i * 16 + quad * 4;
#pragma unroll
    for (int j = 0; j < 4; ++j) {
      const int n = colBase + wx * 64 + j * 16 + r16;
#pragma unroll
      for (int rr = 0; rr < 4; ++rr)
        wcombt[(size_t)(m0 + rr) * 1024 + n] = (bf16_t)acc[i][j][rr];
    }
  }
}

// QKV: 256x256-tile, 512-thread (8 waves 2Mx4N, per-wave 128x64 = m201
// geometry: halves LDS bytes/FLOP vs 64x64). BK=32 with line-paired LDS
// layout: each 128B LDS line holds a row pair; stored slot s (16B) of line L
// holds logical slot s^(L&7), logical slot = (row&1)*4 + kchunk. Same
// slot-distribution class as the verified zero-conflict BK=64 pattern;
// staged linearly via pre-swizzled GLOBAL source addresses.
// 3-deep ring (3 x 32KB = 96KB), prefetch distance 2, 4 issues/K-tile
// (2/phase) -> counted vmcnt(4) at K-tile boundary, never 0 mid-loop.
// 2 phases/K-tile: {ds_read 8|4 x b128, 2 gld_lds, barrier, setprio(1),
// 16 MFMA, setprio(0), barrier}. Grid 384 = 32x12, col-major XCD chunks
// (1.5 col-tiles/XCD -> B slice ~768KB L2-resident).
#define BM2 256
#define BN2 256
#define BK2 32
#define NT2 (1024 / BK2)       // 32
#define SLOT_E 16384           // elems per ring slot: A 256x32 + B 256x32
__global__ void __launch_bounds__(512, 2) k_gemm_qkv(
    const bf16_t* __restrict__ X, const bf16_t* __restrict__ Wt,
    const bf16_t* __restrict__ Wct,
    bf16_t* __restrict__ Q, bf16_t* __restrict__ Kmat, bf16_t* __restrict__ VWt) {
  __shared__ bf16_t lds[3 * SLOT_E];   // 96 KB
  const int l = blockIdx.x;
  const int xcd = l & 7;
  const int sidx = l >> 3;            // 0..47
  const int linb = xcd * 48 + sidx;
  const int by = linb & 31;
  const int bxt = linb >> 5;          // 0..11
  const int rowBase = by * BM2;
  const int colBase = bxt * BN2;
  const int region = colBase >> 10;   // 0=Q 1=K 2=VW (block-uniform)
  const bf16_t* Bt = (region == 2) ? Wct : Wt;
  const int cb = (region == 2) ? (colBase - 2048) : colBase;

  const int t    = threadIdx.x;
  const int lane = t & 63;
  const int wave = t >> 6;          // 0..7
  const int wy   = wave >> 2;       // 0..1 : 128-row band
  const int wx   = wave & 3;        // 0..3 : 64-col band
  const int quad = lane >> 4;
  const int r16  = lane & 15;

  // staging source (pre-swizzled global for the line-paired layout):
  // lane t stores 16B at LDS slot (t&7) of line (t>>3); content must be
  // logical slot slog = (t&7)^((t>>3)&7): row 2*(t>>3)+(slog>>2), chunk slog&3
  const int slog   = (t & 7) ^ ((t >> 3) & 7);
  const int rowoff = 2 * (t >> 3) + (slog >> 2);   // 0..127 within a half
  const int koff   = (slog & 3) * 8;
  const bf16_t* ga = X  + (size_t)(rowBase + rowoff) * 1024 + koff;
  const bf16_t* gb = Bt + (size_t)(cb      + rowoff) * 1024 + koff;

  // frag-read pieces: row r -> line r>>1, slot ((r&1)<<2|quad)^((r>>1)&7)
  const int sl8 = ((((r16 & 1) << 2) | quad) ^ ((r16 >> 1) & 7)) * 8;
  const int rh  = r16 >> 1;

  floatx4 acc[8][4];
#pragma unroll
  for (int i = 0; i < 8; ++i)
#pragma unroll
    for (int j = 0; j < 4; ++j)
      acc[i][j] = (floatx4){0.f, 0.f, 0.f, 0.f};

#define STAGE_A2(KT, DST) {                                                     \
    gld_lds16(ga + (size_t)(KT) * BK2,                        (DST) + t * 8);   \
    gld_lds16(ga + (size_t)(KT) * BK2 + (size_t)128 * 1024,   (DST) + 4096 + t * 8); }
#define STAGE_B2(KT, DST) {                                                     \
    gld_lds16(gb + (size_t)(KT) * BK2,                        (DST) + 8192 + t * 8); \
    gld_lds16(gb + (size_t)(KT) * BK2 + (size_t)128 * 1024,   (DST) + 12288 + t * 8); }

  // prologue: stage tiles 0 and 1 (4 issues each, order A,A,B,B per tile)
  STAGE_A2(0, &lds[0]);
  STAGE_B2(0, &lds[0]);
  STAGE_A2(1, &lds[SLOT_E]);
  STAGE_B2(1, &lds[SLOT_E]);
  asm volatile("s_waitcnt vmcnt(4)" ::: "memory");   // tile 0 landed
  __builtin_amdgcn_s_barrier();
  asm volatile("" ::: "memory");

  for (int kt = 0; kt < NT2; ++kt) {
    const int cur = kt % 3;
    const bf16_t* sa = &lds[cur * SLOT_E];
    const bf16_t* sb = sa + 8192;
    bf16_t* dstg = &lds[((kt + 2) % 3) * SLOT_E];
    const bool pf = (kt + 2) < NT2;

    // ---- phase 0: M-half 0 (frags 0-3) x all N, reads A-half0 + B ----
    {
      bf16x8 af[4], bfr[4];
#pragma unroll
      for (int i = 0; i < 4; ++i)
        af[i] = *(const bf16x8*)(sa + (wy * 64 + i * 8 + rh) * 64 + sl8);
#pragma unroll
      for (int j = 0; j < 4; ++j)
        bfr[j] = *(const bf16x8*)(sb + (wx * 32 + j * 8 + rh) * 64 + sl8);
      if (pf) STAGE_A2(kt + 2, dstg);
      asm volatile("" ::: "memory");
      __builtin_amdgcn_s_barrier();
      __builtin_amdgcn_s_setprio(1);
#pragma unroll
      for (int i = 0; i < 4; ++i)
#pragma unroll
        for (int j = 0; j < 4; ++j)
          acc[i][j] = __builtin_amdgcn_mfma_f32_16x16x32_bf16(af[i], bfr[j], acc[i][j], 0, 0, 0);
      __builtin_amdgcn_s_setprio(0);
      asm volatile("" ::: "memory");
      __builtin_amdgcn_s_barrier();
      asm volatile("" ::: "memory");

      // ---- phase 1: M-half 1 (frags 4-7), reads A-half1; B held in regs ----
      bf16x8 ag[4];
#pragma unroll
      for (int i = 0; i < 4; ++i)
        ag[i] = *(const bf16x8*)(sa + (wy * 64 + 32 + i * 8 + rh) * 64 + sl8);
      if (pf) STAGE_B2(kt + 2, dstg);
      asm volatile("" ::: "memory");
      __builtin_amdgcn_s_barrier();
      __builtin_amdgcn_s_setprio(1);
#pragma unroll
      for (int i = 0; i < 4; ++i)
#pragma unroll
        for (int j = 0; j < 4; ++j)
          acc[4 + i][j] = __builtin_amdgcn_mfma_f32_16x16x32_bf16(ag[i], bfr[j], acc[4 + i][j], 0, 0, 0);
      __builtin_amdgcn_s_setprio(0);
    }

    // ---- K-tile boundary: tile kt+1 must be resident; keep kt+2 in flight ----
    if (kt + 1 < NT2) {
      if (kt + 2 < NT2) { asm volatile("s_waitcnt vmcnt(4)" ::: "memory"); }
      else              { asm volatile("s_waitcnt vmcnt(0)" ::: "memory"); }
      __builtin_amdgcn_s_barrier();
      asm volatile("" ::: "memory");
    }
  }
#undef STAGE_A2
#undef STAGE_B2

  // epilogue: per-wave 128x64 at (rowBase + wy*128, colBase + wx*64)
  if (region < 2) {
    bf16_t* dst = region == 0 ? Q : Kmat;
    const float scale = region == 0 ? 0.03125f : 1.0f;   // fold softmax 1024^-0.5
    const int nb = colBase & 1023;
#pragma unroll
    for (int fi = 0; fi < 8; ++fi) {
      const int m0 = rowBase + wy * 128 + fi * 16 + quad * 4;
#pragma unroll
      for (int j = 0; j < 4; ++j) {
        const int n = nb + wx * 64 + j * 16 + r16;
#pragma unroll
        for (int rr = 0; rr < 4; ++rr)
          dst[(size_t)(m0 + rr) * 1024 + n] = (bf16_t)(acc[fi][j][rr] * scale);
      }
    }
  } else {
    // VWt[b][n][s] = (X @ Wcomb)^T, bf16 (transposed scatter along s)
    const int nb = colBase - 2048;
    const int b = rowBase >> 11;              // 256-row tile: uniform batch
#pragma unroll
    for (int fi = 0; fi < 8; ++fi) {
      const int m0 = rowBase + wy * 128 + fi * 16 + quad * 4;
      const int s0 = m0 & 2047;
#pragma unroll
      for (int j = 0; j < 4; ++j) {
        const int n = nb + wx * 64 + j * 16 + r16;
        bf16x4 pk;
#pragma unroll
        for (int rr = 0; rr < 4; ++rr) pk[rr] = (bf16_t)acc[fi][j][rr];
        *(bf16x4*)(VWt + (size_t)(b * 1024 + n) * 2048 + s0) = pk;
      }
    }
  }
}

// QKEXP: QK^T + exp, causal, 64x128 tiles. 272 tiles/batch x 4 = 1088 blocks.
// Triangular decode: tiles per row-block byp is (byp>>1)+1; prefix(2u)=u(u+1),
// prefix(2u+1)=(u+1)^2. Q pre-scaled so acc == logit (|logit| << 88, no max-sub).
__global__ void __launch_bounds__(256) k_qkexp(
    const bf16_t* __restrict__ Q, const bf16_t* __restrict__ Kmat,
    bf16_t* __restrict__ P, float* __restrict__ rowsum) {
  __shared__ bf16_t ldsA[64 * BK];
  __shared__ bf16_t ldsB[BN * BK];
  floatx4 acc[2][4];
  const int l = blockIdx.x;
  const int b = l / 272;
  const int lin = l - 272 * b;
  int r = (int)sqrtf((float)lin + 0.5f);
  while (r * r > lin) --r;
  while ((r + 1) * (r + 1) <= lin) ++r;
  int byp, bx;
  if (lin >= r * (r + 1)) { byp = 2 * r;     bx = lin - r * (r + 1); }
  else                    { byp = 2 * r - 1; bx = lin - r * r;       }
  const int rowBase = byp * 64, colBase = bx * BN;

  const bf16_t* Ab = Q    + (size_t)b * 2048 * 1024;
  const bf16_t* Bb = Kmat + (size_t)b * 2048 * 1024;
  gemm_bt_core64(Ab, 1024, Bb, 1024, rowBase, colBase, 1024 / BK, ldsA, ldsB, acc);

  bf16_t* Pb = P + (size_t)b * 2048 * 2048;
  float* rs = rowsum + (size_t)b * 2048;
  EPILOGUE_SETUP();
  const bool offdiag = (colBase + BN - 1 <= rowBase);   // whole tile unmasked

  float partial[2][4];
#pragma unroll
  for (int i = 0; i < 2; ++i)
#pragma unroll
    for (int rr = 0; rr < 4; ++rr) partial[i][rr] = 0.f;

#pragma unroll
  for (int i = 0; i < 2; ++i) {
    const int m0 = rowBase + wy * 32 + i * 16 + quad * 4;
#pragma unroll
    for (int j = 0; j < 4; ++j) {
      const int n = colBase + wx * 64 + j * 16 + r16;
#pragma unroll
      for (int rr = 0; rr < 4; ++rr) {
        const int m = m0 + rr;
        const float e = (offdiag || n <= m) ? __expf(acc[i][j][rr]) : 0.0f;
        Pb[(size_t)m * 2048 + n] = (bf16_t)e;
        partial[i][rr] += e;
      }
    }
  }
#pragma unroll
  for (int i = 0; i < 2; ++i)
#pragma unroll
    for (int rr = 0; rr < 4; ++rr) {
      float v = partial[i][rr];
      v += __shfl_xor(v, 1, 64);
      v += __shfl_xor(v, 2, 64);
      v += __shfl_xor(v, 4, 64);
      v += __shfl_xor(v, 8, 64);
      partial[i][rr] = v;
    }
  if (r16 == 0) {
#pragma unroll
    for (int i = 0; i < 2; ++i) {
      const int m0 = rowBase + wy * 32 + i * 16 + quad * 4;
#pragma unroll
      for (int rr = 0; rr < 4; ++rr)
        atomicAdd(&rs[m0 + rr], partial[i][rr]);
    }
  }
}

// POVW: out[b][m][n] = (P_unnorm @ VWt^T) * inv_rowsum + bias, fp32.
// 64x128 tiles: 1024 blocks = 4/CU. Causal bound at 64-row granularity:
// ktiles = by'+1. Per-CU balance: blocks l, l+256, l+512, l+768 get
// by' = {31-w, w, 16+w, 15-w} -> 66 ktiles per CU, constant.
__global__ void __launch_bounds__(256) k_gemm_povw(
    const bf16_t* __restrict__ P, const bf16_t* __restrict__ VWt,
    const float* __restrict__ rowsum, const float* __restrict__ bias,
    float* __restrict__ out) {
  const int l = blockIdx.x;
  const int z = l >> 8;
  const int idx = l & 255;
  const int bx = idx & 7;
  const int w = (idx >> 3) & 7;
  const int b = idx >> 6;
  const int byp = (z == 0) ? (31 - w) : (z == 1) ? w : (z == 2) ? (16 + w) : (15 - w);

  __shared__ bf16_t ldsA[64 * BK];
  __shared__ bf16_t ldsB[BN * BK];
  floatx4 acc[2][4];
  const bf16_t* Ab = P + (size_t)b * 2048 * 2048;
  const bf16_t* Bb = VWt + (size_t)b * 1024 * 2048;
  const int rowBase = byp * 64, colBase = bx * BN;
  gemm_bt_core64(Ab, 2048, Bb, 2048, rowBase, colBase, byp + 1, ldsA, ldsB, acc);
  const float* rs = rowsum + (size_t)b * 2048;
  EPILOGUE_SETUP();
#pragma unroll
  for (int i = 0; i < 2; ++i) {
    const int m0 = rowBase + wy * 32 + i * 16 + quad * 4;
#pragma unroll
    for (int rr = 0; rr < 4; ++rr) {
      const float inv = 1.0f / rs[m0 + rr];
      const size_t row = (size_t)b * 2048 + m0 + rr;
#pragma unroll
      for (int j = 0; j < 4; ++j) {
        const int n = colBase + wx * 64 + j * 16 + r16;
        out[row * 1024 + n] = acc[i][j][rr] * inv + bias[n];
      }
    }
  }
}

// ---------------- launch ----------------
// ws layout (bytes):
//   xb     @ 0          16,777,216   x as bf16 [8192,1024]
//   wqkvt  @ 16777216    6,291,456   w_qkv^T bf16 [3072,1024] (Q,K halves used)
//   woutt  @ 23068672    2,097,152   w_out^T bf16 [1024,1024]
//   q      @ 25165824   16,777,216   [b,s,1024] bf16 (pre-scaled by 2^-5)
//   k      @ 41943040   16,777,216   [b,s,1024] bf16
//   wvb    @ 58720256    2,097,152   Wv = w_qkv[:,2048:3072] bf16 row-major
//   wcombt @ 60817408    2,097,152   (Wv @ Wout)^T bf16 [1024,1024]
//   rowsum @ 75497472       32,768   [b,s] fp32 sum of exp
//   p      @ 142606336  33,554,432   [b,s,s] bf16 unnormalized exp(logit)
//   vwt    @ 176160768  16,777,216   [b,1024(n),s] bf16 (X@Wcomb transposed)
extern "C" void kernel_launch(void* const* d_in, const int* in_sizes, int n_in,
                              void* d_out, int out_size, void* d_ws, size_t ws_size,
                              hipStream_t stream) {
  const float* x     = (const float*)d_in[0];
  const float* w_qkv = (const float*)d_in[1];
  const float* w_out = (const float*)d_in[2];
  const float* b_out = (const float*)d_in[3];
  float* out = (float*)d_out;
  char* ws = (char*)d_ws;

  bf16_t* xb     = (bf16_t*)(ws + 0);
  bf16_t* wqt    = (bf16_t*)(ws + 16777216);
  bf16_t* wot    = (bf16_t*)(ws + 23068672);
  bf16_t* q      = (bf16_t*)(ws + 25165824);
  bf16_t* kmat   = (bf16_t*)(ws + 41943040);
  bf16_t* wvb    = (bf16_t*)(ws + 58720256);
  bf16_t* wcombt = (bf16_t*)(ws + 60817408);
  float*  rowsum = (float*)(ws + 75497472);
  bf16_t* p      = (bf16_t*)(ws + 142606336);
  bf16_t* vwt    = (bf16_t*)(ws + 176160768);

  k_prep<<<8704, 256, 0, stream>>>(x, xb, w_qkv, wqt, w_out, wot, rowsum, wvb);
  k_wcomb<<<128, 256, 0, stream>>>(wot, wvb, wcombt);
  k_gemm_qkv<<<384, 512, 0, stream>>>(xb, wqt, wcombt, q, kmat, vwt);
  k_qkexp<<<1088, 256, 0, stream>>>(q, kmat, p, rowsum);
  k_gemm_povw<<<1024, 256, 0, stream>>>(p, vwt, rowsum, b_out, out);
}

// Round 4
// 239.444 us; speedup vs baseline: 1.1037x; 1.1037x over previous
//
#include <hip/hip_runtime.h>

typedef __bf16 bf16_t;
typedef __bf16 bf16x8 __attribute__((ext_vector_type(8)));
typedef __bf16 bf16x4 __attribute__((ext_vector_type(4)));
typedef float  floatx4 __attribute__((ext_vector_type(4)));

#define BM 128
#define BN 128
#define BK 64

// async global->LDS, 16B per lane. LDS dest is wave-uniform base + lane*16 (no
// scatter, no padding) — conflict-avoidance is done by permuting the GLOBAL
// chunk each lane fetches (XOR swizzle), not the LDS address.
__device__ __forceinline__ void gld_lds16(const bf16_t* g, bf16_t* l) {
  __builtin_amdgcn_global_load_lds(
      (__attribute__((address_space(1))) const void*)g,
      (__attribute__((address_space(3))) void*)l, 16, 0, 0);
}

// 64x128 variant: BM=64, BN=128, waves 2x2 each 32x64, acc[2][4].
// LDS row-major [rows][BK=64]; chunk s of row r holds global chunk s^(r&7).
__device__ __forceinline__ void gemm_bt_core64(
    const bf16_t* __restrict__ A, int lda,
    const bf16_t* __restrict__ Bt, int ldb,
    int rowBase, int colBase, int kTiles,
    bf16_t* ldsA, bf16_t* ldsB, floatx4 acc[2][4])
{
  const int t    = threadIdx.x;
  const int lane = t & 63;
  const int wave = t >> 6;
  const int wy   = wave >> 1;      // 32-row half
  const int wx   = wave & 1;       // 64-col half
  const int quad = lane >> 4;
  const int r16  = lane & 15;

  const int srow   = t >> 3;
  const int schunk = (t & 7) ^ (srow & 7);
  const bf16_t* ga = A  + (size_t)(rowBase + srow) * lda + schunk * 8;
  const bf16_t* gb = Bt + (size_t)(colBase + srow) * ldb + schunk * 8;
  bf16_t* la = ldsA + t * 8;
  bf16_t* lb = ldsB + t * 8;

#pragma unroll
  for (int i = 0; i < 2; ++i)
#pragma unroll
    for (int j = 0; j < 4; ++j)
      acc[i][j] = (floatx4){0.f, 0.f, 0.f, 0.f};

  for (int kt = 0; kt < kTiles; ++kt) {
    const int k0 = kt * BK;
    gld_lds16(ga + k0,                    la);             // A: 64 rows = 2 issues
    gld_lds16(ga + k0 + (size_t)32 * lda, la + 32 * BK);
#pragma unroll
    for (int is = 0; is < 4; ++is)                         // B: 128 rows = 4 issues
      gld_lds16(gb + k0 + (size_t)(32 * is) * ldb, lb + is * (32 * BK));
    __syncthreads();

#pragma unroll
    for (int h = 0; h < 2; ++h) {
      bf16x8 af[2], bfr[4];
#pragma unroll
      for (int i = 0; i < 2; ++i) {
        const int r = wy * 32 + i * 16 + r16;
        af[i] = *(const bf16x8*)(ldsA + r * BK + (((h << 2) + quad) ^ (r16 & 7)) * 8);
      }
#pragma unroll
      for (int j = 0; j < 4; ++j) {
        const int r = wx * 64 + j * 16 + r16;
        bfr[j] = *(const bf16x8*)(ldsB + r * BK + (((h << 2) + quad) ^ (r16 & 7)) * 8);
      }
#pragma unroll
      for (int i = 0; i < 2; ++i)
#pragma unroll
        for (int j = 0; j < 4; ++j)
          acc[i][j] = __builtin_amdgcn_mfma_f32_16x16x32_bf16(af[i], bfr[j], acc[i][j], 0, 0, 0);
    }
    __syncthreads();
  }
}

#define EPILOGUE_SETUP()                       \
  const int t    = threadIdx.x;                \
  const int lane = t & 63;                     \
  const int wave = t >> 6;                     \
  const int wy   = wave >> 1;                  \
  const int wx   = wave & 1;                   \
  const int quad = lane >> 4;                  \
  const int r16  = lane & 15;

// ---------------- fused prep kernel ----------------
// blocks [0,4096): x fp32 -> bf16, 8 elems/thread; blocks [0,32) also zero rowsum
// blocks [4096,7168): transpose+cvt w_qkv [1024,3072] -> [3072,1024]
// blocks [7168,8192): transpose+cvt w_out [1024,1024] -> [1024,1024]
// blocks [8192,8704): strided cvt w_qkv[:,2048:3072] -> wvb[1024,1024] bf16
//                     (row-major Wv, no transpose — feeds k_wcomb's Bt)
__global__ void __launch_bounds__(256) k_prep(
    const float* __restrict__ x, bf16_t* __restrict__ xb,
    const float* __restrict__ w_qkv, bf16_t* __restrict__ wqt,
    const float* __restrict__ w_out, bf16_t* __restrict__ wot,
    float* __restrict__ rowsum, bf16_t* __restrict__ wvb) {
  __shared__ float tile[32][33];
  const int bxk = blockIdx.x;
  const int t = threadIdx.x;
  if (bxk < 4096) {
    const size_t idx = (size_t)bxk * 256 + t;
    if (bxk < 32) rowsum[idx] = 0.0f;
    const float4 v0 = ((const float4*)x)[idx * 2];
    const float4 v1 = ((const float4*)x)[idx * 2 + 1];
    bf16x8 o;
    o[0] = (bf16_t)v0.x; o[1] = (bf16_t)v0.y; o[2] = (bf16_t)v0.z; o[3] = (bf16_t)v0.w;
    o[4] = (bf16_t)v1.x; o[5] = (bf16_t)v1.y; o[6] = (bf16_t)v1.z; o[7] = (bf16_t)v1.w;
    ((bf16x8*)xb)[idx] = o;
    return;
  }
  if (bxk >= 8192) {
    const int tb = bxk - 8192;
    const size_t idx = (size_t)tb * 2048 + (size_t)t * 8;   // idx = d*1024 + e
    const int d = (int)(idx >> 10);
    const int e = (int)(idx & 1023);
    const float* src = w_qkv + (size_t)d * 3072 + 2048 + e;
    const float4 v0 = *(const float4*)src;
    const float4 v1 = *(const float4*)(src + 4);
    bf16x8 o;
    o[0] = (bf16_t)v0.x; o[1] = (bf16_t)v0.y; o[2] = (bf16_t)v0.z; o[3] = (bf16_t)v0.w;
    o[4] = (bf16_t)v1.x; o[5] = (bf16_t)v1.y; o[6] = (bf16_t)v1.z; o[7] = (bf16_t)v1.w;
    *(bf16x8*)(wvb + idx) = o;
    return;
  }
  const bool first = bxk < 7168;
  const int tb = first ? (bxk - 4096) : (bxk - 7168);
  const float* in = first ? w_qkv : w_out;
  bf16_t* out = first ? wqt : wot;
  const int C = first ? 3072 : 1024;
  const int nCB = C >> 5;
  const int c0 = (tb % nCB) * 32;
  const int r0 = (tb / nCB) * 32;
  const int tx = t & 31, ty = t >> 5;
#pragma unroll
  for (int rr = 0; rr < 32; rr += 8)
    tile[ty + rr][tx] = in[(size_t)(r0 + ty + rr) * C + (c0 + tx)];
  __syncthreads();
#pragma unroll
  for (int cc = 0; cc < 32; cc += 8)
    out[(size_t)(c0 + ty + cc) * 1024 + (r0 + tx)] = (bf16_t)tile[tx][ty + cc];
}

// ---------------- GEMM kernels ----------------

// WCOMB: wcombt[n,d] = sum_e wot[n,e] * wvb[d,e] = (Wv @ Wout)^T.
// 2.1 GFLOP on 128 blocks — replaces the 17.2-GFLOP VW GEMM because
// V is only ever consumed as V@Wout: X@(Wv@Wout) == (X@Wv)@Wout.
__global__ void __launch_bounds__(256) k_wcomb(
    const bf16_t* __restrict__ wot, const bf16_t* __restrict__ wvb,
    bf16_t* __restrict__ wcombt) {
  __shared__ bf16_t ldsA[64 * BK];
  __shared__ bf16_t ldsB[BN * BK];
  floatx4 acc[2][4];
  const int l = blockIdx.x;
  const int by = l >> 3, bx = l & 7;
  const int rowBase = by * 64, colBase = bx * BN;
  gemm_bt_core64(wot, 1024, wvb, 1024, rowBase, colBase, 1024 / BK, ldsA, ldsB, acc);
  EPILOGUE_SETUP();
#pragma unroll
  for (int i = 0; i < 2; ++i) {
    const int m0 = rowBase + wy * 32 + i * 16 + quad * 4;
#pragma unroll
    for (int j = 0; j < 4; ++j) {
      const int n = colBase + wx * 64 + j * 16 + r16;
#pragma unroll
      for (int rr = 0; rr < 4; ++rr)
        wcombt[(size_t)(m0 + rr) * 1024 + n] = (bf16_t)acc[i][j][rr];
    }
  }
}

// QKV: 256x128-tile, 256-thread (4 waves 2Mx2N, per-wave 128x64 = m201
// fragment geometry: 0.375 ds_read_b128/MFMA vs 0.5 at 64x64). BK=32 with
// line-paired LDS layout: each 128B LDS line = a row pair; stored slot s of
// line L holds logical slot s^(L&7), logical slot = (row&1)*4 + kchunk.
// Measured ZERO bank conflicts in R2. Staged linearly via pre-swizzled
// GLOBAL source addresses. 3-deep ring (3 x 24KB = 72KB -> 2 blocks/CU:
// two desynced blocks/CU hide each other's barrier drains — the R1/R2
// 1-block/CU lockstep couldn't). Prefetch distance 2, 6 issues/K-tile
// (3/phase) -> counted vmcnt(6) at K-tile boundary, never 0 mid-loop.
// Grid 32x24 = 768 = exactly 3 CU rounds (R2's 1.5-round tail was the
// whole regression). XCD-aware: xcd owns 3 col-tiles (B slice 768KB,
// L2-resident). 3072 cols = Q (pre-scaled 2^-5), K, VW; region 2 uses
// wcombt and writes the transposed VWt scatter.
#define BK2 32
#define NT2 (1024 / BK2)       // 32
#define SLOT_E 12288           // elems per ring slot: A 256x32 + B 128x32
__global__ void __launch_bounds__(256, 2) k_gemm_qkv(
    const bf16_t* __restrict__ X, const bf16_t* __restrict__ Wt,
    const bf16_t* __restrict__ Wct,
    bf16_t* __restrict__ Q, bf16_t* __restrict__ Kmat, bf16_t* __restrict__ VWt) {
  __shared__ bf16_t lds[3 * SLOT_E];   // 72 KB
  const int l = blockIdx.x;
  const int xcd = l & 7;
  const int s = l >> 3;               // 0..95
  const int bx = xcd * 3 + (s % 3);   // 0..23
  const int by = s / 3;               // 0..31
  const int rowBase = by * 256;
  const int colBase = bx * 128;
  const int region = colBase >> 10;   // 0=Q 1=K 2=VW (block-uniform)
  const bf16_t* Bt = (region == 2) ? Wct : Wt;
  const int cb = (region == 2) ? (colBase - 2048) : colBase;

  const int t    = threadIdx.x;
  const int lane = t & 63;
  const int wave = t >> 6;          // 0..3
  const int wy   = wave >> 1;       // 0..1 : 128-row band
  const int wx   = wave & 1;        // 0..1 : 64-col band
  const int quad = lane >> 4;
  const int r16  = lane & 15;

  // staging source (pre-swizzled global for the line-paired layout):
  // lane t stores 16B at LDS slot (t&7) of line (t>>3); content must be
  // logical slot slog=(t&7)^((t>>3)&7): row 2*(t>>3)+(slog>>2), chunk slog&3
  const int slog   = (t & 7) ^ ((t >> 3) & 7);
  const int rowoff = 2 * (t >> 3) + (slog >> 2);   // 0..63 per issue
  const int koff   = (slog & 3) * 8;
  const bf16_t* ga = X  + (size_t)(rowBase + rowoff) * 1024 + koff;
  const bf16_t* gb = Bt + (size_t)(cb      + rowoff) * 1024 + koff;

  // frag-read pieces: row r -> line r>>1, slot ((r&1)<<2|quad)^((r>>1)&7)
  const int sl8 = ((((r16 & 1) << 2) | quad) ^ ((r16 >> 1) & 7)) * 8;
  const int rh  = r16 >> 1;

  floatx4 acc[8][4];
#pragma unroll
  for (int i = 0; i < 8; ++i)
#pragma unroll
    for (int j = 0; j < 4; ++j)
      acc[i][j] = (floatx4){0.f, 0.f, 0.f, 0.f};

  // A: 256 rows = 4 issues (64 rows each); B: 128 rows = 2 issues
#define STAGE_A3(KT, DST) {                                                       \
    gld_lds16(ga + (size_t)(KT) * BK2,                        (DST) + t * 8);     \
    gld_lds16(ga + (size_t)(KT) * BK2 + (size_t) 64 * 1024,   (DST) + 2048 + t * 8); \
    gld_lds16(ga + (size_t)(KT) * BK2 + (size_t)128 * 1024,   (DST) + 4096 + t * 8); }
#define STAGE_A1B2(KT, DST) {                                                     \
    gld_lds16(ga + (size_t)(KT) * BK2 + (size_t)192 * 1024,   (DST) + 6144 + t * 8); \
    gld_lds16(gb + (size_t)(KT) * BK2,                        (DST) + 8192 + t * 8); \
    gld_lds16(gb + (size_t)(KT) * BK2 + (size_t) 64 * 1024,   (DST) + 10240 + t * 8); }

  // prologue: stage tiles 0 and 1 (6 issues each)
  STAGE_A3(0, &lds[0]);
  STAGE_A1B2(0, &lds[0]);
  STAGE_A3(1, &lds[SLOT_E]);
  STAGE_A1B2(1, &lds[SLOT_E]);
  asm volatile("s_waitcnt vmcnt(6)" ::: "memory");   // tile 0 landed
  __builtin_amdgcn_s_barrier();
  asm volatile("" ::: "memory");

  for (int kt = 0; kt < NT2; ++kt) {
    const int cur = kt % 3;
    const bf16_t* sa = &lds[cur * SLOT_E];
    const bf16_t* sb = sa + 8192;
    bf16_t* dstg = &lds[((kt + 2) % 3) * SLOT_E];
    const bool pf = (kt + 2) < NT2;

    // ---- phase 0: M-half 0 (frags 0-3) x all N, reads A-half0 + B ----
    bf16x8 af[4], bfr[4];
#pragma unroll
    for (int i = 0; i < 4; ++i)
      af[i] = *(const bf16x8*)(sa + (wy * 64 + i * 8 + rh) * 64 + sl8);
#pragma unroll
    for (int j = 0; j < 4; ++j)
      bfr[j] = *(const bf16x8*)(sb + (wx * 32 + j * 8 + rh) * 64 + sl8);
    if (pf) STAGE_A3(kt + 2, dstg);
    asm volatile("" ::: "memory");
    __builtin_amdgcn_s_barrier();
    __builtin_amdgcn_s_setprio(1);
#pragma unroll
    for (int i = 0; i < 4; ++i)
#pragma unroll
      for (int j = 0; j < 4; ++j)
        acc[i][j] = __builtin_amdgcn_mfma_f32_16x16x32_bf16(af[i], bfr[j], acc[i][j], 0, 0, 0);
    __builtin_amdgcn_s_setprio(0);
    asm volatile("" ::: "memory");
    __builtin_amdgcn_s_barrier();
    asm volatile("" ::: "memory");

    // ---- phase 1: M-half 1 (frags 4-7), reads A-half1; B held in regs ----
    bf16x8 ag[4];
#pragma unroll
    for (int i = 0; i < 4; ++i)
      ag[i] = *(const bf16x8*)(sa + (wy * 64 + 32 + i * 8 + rh) * 64 + sl8);
    if (pf) STAGE_A1B2(kt + 2, dstg);
    asm volatile("" ::: "memory");
    __builtin_amdgcn_s_barrier();
    __builtin_amdgcn_s_setprio(1);
#pragma unroll
    for (int i = 0; i < 4; ++i)
#pragma unroll
      for (int j = 0; j < 4; ++j)
        acc[4 + i][j] = __builtin_amdgcn_mfma_f32_16x16x32_bf16(ag[i], bfr[j], acc[4 + i][j], 0, 0, 0);
    __builtin_amdgcn_s_setprio(0);

    // ---- K-tile boundary: tile kt+1 must be resident; keep kt+2 in flight ----
    if (kt + 1 < NT2) {
      if (kt + 2 < NT2) { asm volatile("s_waitcnt vmcnt(6)" ::: "memory"); }
      else              { asm volatile("s_waitcnt vmcnt(0)" ::: "memory"); }
      __builtin_amdgcn_s_barrier();
      asm volatile("" ::: "memory");
    }
  }
#undef STAGE_A3
#undef STAGE_A1B2

  // epilogue: per-wave 128x64 at (rowBase + wy*128, colBase + wx*64)
  if (region < 2) {
    bf16_t* dst = region == 0 ? Q : Kmat;
    const float scale = region == 0 ? 0.03125f : 1.0f;   // fold softmax 1024^-0.5
    const int nb = colBase & 1023;
#pragma unroll
    for (int fi = 0; fi < 8; ++fi) {
      const int m0 = rowBase + wy * 128 + fi * 16 + quad * 4;
#pragma unroll
      for (int j = 0; j < 4; ++j) {
        const int n = nb + wx * 64 + j * 16 + r16;
#pragma unroll
        for (int rr = 0; rr < 4; ++rr)
          dst[(size_t)(m0 + rr) * 1024 + n] = (bf16_t)(acc[fi][j][rr] * scale);
      }
    }
  } else {
    // VWt[b][n][s] = (X @ Wcomb)^T, bf16 (transposed scatter along s)
    const int nb = colBase - 2048;
    const int b = rowBase >> 11;              // 256-row tile: uniform batch
#pragma unroll
    for (int fi = 0; fi < 8; ++fi) {
      const int m0 = rowBase + wy * 128 + fi * 16 + quad * 4;
      const int s0 = m0 & 2047;
#pragma unroll
      for (int j = 0; j < 4; ++j) {
        const int n = nb + wx * 64 + j * 16 + r16;
        bf16x4 pk;
#pragma unroll
        for (int rr = 0; rr < 4; ++rr) pk[rr] = (bf16_t)acc[fi][j][rr];
        *(bf16x4*)(VWt + (size_t)(b * 1024 + n) * 2048 + s0) = pk;
      }
    }
  }
}

// QKEXP: QK^T + exp, causal, 64x128 tiles. 272 tiles/batch x 4 = 1088 blocks.
// Triangular decode: tiles per row-block byp is (byp>>1)+1; prefix(2u)=u(u+1),
// prefix(2u+1)=(u+1)^2. Q pre-scaled so acc == logit (|logit| << 88, no max-sub).
__global__ void __launch_bounds__(256) k_qkexp(
    const bf16_t* __restrict__ Q, const bf16_t* __restrict__ Kmat,
    bf16_t* __restrict__ P, float* __restrict__ rowsum) {
  __shared__ bf16_t ldsA[64 * BK];
  __shared__ bf16_t ldsB[BN * BK];
  floatx4 acc[2][4];
  const int l = blockIdx.x;
  const int b = l / 272;
  const int lin = l - 272 * b;
  int r = (int)sqrtf((float)lin + 0.5f);
  while (r * r > lin) --r;
  while ((r + 1) * (r + 1) <= lin) ++r;
  int byp, bx;
  if (lin >= r * (r + 1)) { byp = 2 * r;     bx = lin - r * (r + 1); }
  else                    { byp = 2 * r - 1; bx = lin - r * r;       }
  const int rowBase = byp * 64, colBase = bx * BN;

  const bf16_t* Ab = Q    + (size_t)b * 2048 * 1024;
  const bf16_t* Bb = Kmat + (size_t)b * 2048 * 1024;
  gemm_bt_core64(Ab, 1024, Bb, 1024, rowBase, colBase, 1024 / BK, ldsA, ldsB, acc);

  bf16_t* Pb = P + (size_t)b * 2048 * 2048;
  float* rs = rowsum + (size_t)b * 2048;
  EPILOGUE_SETUP();
  const bool offdiag = (colBase + BN - 1 <= rowBase);   // whole tile unmasked

  float partial[2][4];
#pragma unroll
  for (int i = 0; i < 2; ++i)
#pragma unroll
    for (int rr = 0; rr < 4; ++rr) partial[i][rr] = 0.f;

#pragma unroll
  for (int i = 0; i < 2; ++i) {
    const int m0 = rowBase + wy * 32 + i * 16 + quad * 4;
#pragma unroll
    for (int j = 0; j < 4; ++j) {
      const int n = colBase + wx * 64 + j * 16 + r16;
#pragma unroll
      for (int rr = 0; rr < 4; ++rr) {
        const int m = m0 + rr;
        const float e = (offdiag || n <= m) ? __expf(acc[i][j][rr]) : 0.0f;
        Pb[(size_t)m * 2048 + n] = (bf16_t)e;
        partial[i][rr] += e;
      }
    }
  }
#pragma unroll
  for (int i = 0; i < 2; ++i)
#pragma unroll
    for (int rr = 0; rr < 4; ++rr) {
      float v = partial[i][rr];
      v += __shfl_xor(v, 1, 64);
      v += __shfl_xor(v, 2, 64);
      v += __shfl_xor(v, 4, 64);
      v += __shfl_xor(v, 8, 64);
      partial[i][rr] = v;
    }
  if (r16 == 0) {
#pragma unroll
    for (int i = 0; i < 2; ++i) {
      const int m0 = rowBase + wy * 32 + i * 16 + quad * 4;
#pragma unroll
      for (int rr = 0; rr < 4; ++rr)
        atomicAdd(&rs[m0 + rr], partial[i][rr]);
    }
  }
}

// POVW: out[b][m][n] = (P_unnorm @ VWt^T) * inv_rowsum + bias, fp32.
// 64x128 tiles: 1024 blocks = 4/CU. Causal bound at 64-row granularity:
// ktiles = by'+1. Per-CU balance: blocks l, l+256, l+512, l+768 get
// by' = {31-w, w, 16+w, 15-w} -> 66 ktiles per CU, constant.
__global__ void __launch_bounds__(256) k_gemm_povw(
    const bf16_t* __restrict__ P, const bf16_t* __restrict__ VWt,
    const float* __restrict__ rowsum, const float* __restrict__ bias,
    float* __restrict__ out) {
  const int l = blockIdx.x;
  const int z = l >> 8;
  const int idx = l & 255;
  const int bx = idx & 7;
  const int w = (idx >> 3) & 7;
  const int b = idx >> 6;
  const int byp = (z == 0) ? (31 - w) : (z == 1) ? w : (z == 2) ? (16 + w) : (15 - w);

  __shared__ bf16_t ldsA[64 * BK];
  __shared__ bf16_t ldsB[BN * BK];
  floatx4 acc[2][4];
  const bf16_t* Ab = P + (size_t)b * 2048 * 2048;
  const bf16_t* Bb = VWt + (size_t)b * 1024 * 2048;
  const int rowBase = byp * 64, colBase = bx * BN;
  gemm_bt_core64(Ab, 2048, Bb, 2048, rowBase, colBase, byp + 1, ldsA, ldsB, acc);
  const float* rs = rowsum + (size_t)b * 2048;
  EPILOGUE_SETUP();
#pragma unroll
  for (int i = 0; i < 2; ++i) {
    const int m0 = rowBase + wy * 32 + i * 16 + quad * 4;
#pragma unroll
    for (int rr = 0; rr < 4; ++rr) {
      const float inv = 1.0f / rs[m0 + rr];
      const size_t row = (size_t)b * 2048 + m0 + rr;
#pragma unroll
      for (int j = 0; j < 4; ++j) {
        const int n = colBase + wx * 64 + j * 16 + r16;
        out[row * 1024 + n] = acc[i][j][rr] * inv + bias[n];
      }
    }
  }
}

// ---------------- launch ----------------
// ws layout (bytes):
//   xb     @ 0          16,777,216   x as bf16 [8192,1024]
//   wqkvt  @ 16777216    6,291,456   w_qkv^T bf16 [3072,1024] (Q,K halves used)
//   woutt  @ 23068672    2,097,152   w_out^T bf16 [1024,1024]
//   q      @ 25165824   16,777,216   [b,s,1024] bf16 (pre-scaled by 2^-5)
//   k      @ 41943040   16,777,216   [b,s,1024] bf16
//   wvb    @ 58720256    2,097,152   Wv = w_qkv[:,2048:3072] bf16 row-major
//   wcombt @ 60817408    2,097,152   (Wv @ Wout)^T bf16 [1024,1024]
//   rowsum @ 75497472       32,768   [b,s] fp32 sum of exp
//   p      @ 142606336  33,554,432   [b,s,s] bf16 unnormalized exp(logit)
//   vwt    @ 176160768  16,777,216   [b,1024(n),s] bf16 (X@Wcomb transposed)
extern "C" void kernel_launch(void* const* d_in, const int* in_sizes, int n_in,
                              void* d_out, int out_size, void* d_ws, size_t ws_size,
                              hipStream_t stream) {
  const float* x     = (const float*)d_in[0];
  const float* w_qkv = (const float*)d_in[1];
  const float* w_out = (const float*)d_in[2];
  const float* b_out = (const float*)d_in[3];
  float* out = (float*)d_out;
  char* ws = (char*)d_ws;

  bf16_t* xb     = (bf16_t*)(ws + 0);
  bf16_t* wqt    = (bf16_t*)(ws + 16777216);
  bf16_t* wot    = (bf16_t*)(ws + 23068672);
  bf16_t* q      = (bf16_t*)(ws + 25165824);
  bf16_t* kmat   = (bf16_t*)(ws + 41943040);
  bf16_t* wvb    = (bf16_t*)(ws + 58720256);
  bf16_t* wcombt = (bf16_t*)(ws + 60817408);
  float*  rowsum = (float*)(ws + 75497472);
  bf16_t* p      = (bf16_t*)(ws + 142606336);
  bf16_t* vwt    = (bf16_t*)(ws + 176160768);

  k_prep<<<8704, 256, 0, stream>>>(x, xb, w_qkv, wqt, w_out, wot, rowsum, wvb);
  k_wcomb<<<128, 256, 0, stream>>>(wot, wvb, wcombt);
  k_gemm_qkv<<<768, 256, 0, stream>>>(xb, wqt, wcombt, q, kmat, vwt);
  k_qkexp<<<1088, 256, 0, stream>>>(q, kmat, p, rowsum);
  k_gemm_povw<<<1024, 256, 0, stream>>>(p, vwt, rowsum, b_out, out);
}

// Round 5
// 224.815 us; speedup vs baseline: 1.1755x; 1.0651x over previous
//
#include <hip/hip_runtime.h>

typedef __bf16 bf16_t;
typedef __bf16 bf16x8 __attribute__((ext_vector_type(8)));
typedef __bf16 bf16x4 __attribute__((ext_vector_type(4)));
typedef float  floatx4 __attribute__((ext_vector_type(4)));

#define BM 128
#define BN 128
#define BK 64

// async global->LDS, 16B per lane. LDS dest is wave-uniform base + lane*16 (no
// scatter, no padding) — conflict-avoidance is done by permuting the GLOBAL
// chunk each lane fetches (XOR swizzle), not the LDS address.
__device__ __forceinline__ void gld_lds16(const bf16_t* g, bf16_t* l) {
  __builtin_amdgcn_global_load_lds(
      (__attribute__((address_space(1))) const void*)g,
      (__attribute__((address_space(3))) void*)l, 16, 0, 0);
}

// 64x128 variant: BM=64, BN=128, waves 2x2 each 32x64, acc[2][4].
// LDS row-major [rows][BK=64]; chunk s of row r holds global chunk s^(r&7).
__device__ __forceinline__ void gemm_bt_core64(
    const bf16_t* __restrict__ A, int lda,
    const bf16_t* __restrict__ Bt, int ldb,
    int rowBase, int colBase, int kTiles,
    bf16_t* ldsA, bf16_t* ldsB, floatx4 acc[2][4])
{
  const int t    = threadIdx.x;
  const int lane = t & 63;
  const int wave = t >> 6;
  const int wy   = wave >> 1;      // 32-row half
  const int wx   = wave & 1;       // 64-col half
  const int quad = lane >> 4;
  const int r16  = lane & 15;

  const int srow   = t >> 3;
  const int schunk = (t & 7) ^ (srow & 7);
  const bf16_t* ga = A  + (size_t)(rowBase + srow) * lda + schunk * 8;
  const bf16_t* gb = Bt + (size_t)(colBase + srow) * ldb + schunk * 8;
  bf16_t* la = ldsA + t * 8;
  bf16_t* lb = ldsB + t * 8;

#pragma unroll
  for (int i = 0; i < 2; ++i)
#pragma unroll
    for (int j = 0; j < 4; ++j)
      acc[i][j] = (floatx4){0.f, 0.f, 0.f, 0.f};

  for (int kt = 0; kt < kTiles; ++kt) {
    const int k0 = kt * BK;
    gld_lds16(ga + k0,                    la);             // A: 64 rows = 2 issues
    gld_lds16(ga + k0 + (size_t)32 * lda, la + 32 * BK);
#pragma unroll
    for (int is = 0; is < 4; ++is)                         // B: 128 rows = 4 issues
      gld_lds16(gb + k0 + (size_t)(32 * is) * ldb, lb + is * (32 * BK));
    __syncthreads();

#pragma unroll
    for (int h = 0; h < 2; ++h) {
      bf16x8 af[2], bfr[4];
#pragma unroll
      for (int i = 0; i < 2; ++i) {
        const int r = wy * 32 + i * 16 + r16;
        af[i] = *(const bf16x8*)(ldsA + r * BK + (((h << 2) + quad) ^ (r16 & 7)) * 8);
      }
#pragma unroll
      for (int j = 0; j < 4; ++j) {
        const int r = wx * 64 + j * 16 + r16;
        bfr[j] = *(const bf16x8*)(ldsB + r * BK + (((h << 2) + quad) ^ (r16 & 7)) * 8);
      }
#pragma unroll
      for (int i = 0; i < 2; ++i)
#pragma unroll
        for (int j = 0; j < 4; ++j)
          acc[i][j] = __builtin_amdgcn_mfma_f32_16x16x32_bf16(af[i], bfr[j], acc[i][j], 0, 0, 0);
    }
    __syncthreads();
  }
}

#define EPILOGUE_SETUP()                       \
  const int t    = threadIdx.x;                \
  const int lane = t & 63;                     \
  const int wave = t >> 6;                     \
  const int wy   = wave >> 1;                  \
  const int wx   = wave & 1;                   \
  const int quad = lane >> 4;                  \
  const int r16  = lane & 15;

// ---------------- fused prep kernel ----------------
// blocks [0,4096): x fp32 -> bf16, 8 elems/thread; blocks [0,32) also zero rowsum
// blocks [4096,5120): transpose+cvt w_out [1024,1024] -> wot [1024,1024]
// blocks [5120,6656): strided cvt of w_qkv column slices (row-major, no transpose):
//   grp 0: wvb = w_qkv[:,2048:3072]  grp 1: wqb = w_qkv[:,0:1024]
//   grp 2: wkb = w_qkv[:,1024:2048]
// The w_qkv transpose is GONE: Q/K GEMMs are folded into Wqk = Wq@Wk^T
// (sim = X (Wq Wk^T) X^T), so only row-major weight slices are needed.
__global__ void __launch_bounds__(256) k_prep(
    const float* __restrict__ x, bf16_t* __restrict__ xb,
    const float* __restrict__ w_qkv, const float* __restrict__ w_out,
    bf16_t* __restrict__ wot, float* __restrict__ rowsum,
    bf16_t* __restrict__ wvb, bf16_t* __restrict__ wqb, bf16_t* __restrict__ wkb) {
  __shared__ float tile[32][33];
  const int bxk = blockIdx.x;
  const int t = threadIdx.x;
  if (bxk < 4096) {
    const size_t idx = (size_t)bxk * 256 + t;
    if (bxk < 32) rowsum[idx] = 0.0f;
    const float4 v0 = ((const float4*)x)[idx * 2];
    const float4 v1 = ((const float4*)x)[idx * 2 + 1];
    bf16x8 o;
    o[0] = (bf16_t)v0.x; o[1] = (bf16_t)v0.y; o[2] = (bf16_t)v0.z; o[3] = (bf16_t)v0.w;
    o[4] = (bf16_t)v1.x; o[5] = (bf16_t)v1.y; o[6] = (bf16_t)v1.z; o[7] = (bf16_t)v1.w;
    ((bf16x8*)xb)[idx] = o;
    return;
  }
  if (bxk >= 5120) {
    const int ridx = bxk - 5120;
    const int grp = ridx >> 9;          // 0,1,2
    const int tb  = ridx & 511;
    const int off = grp == 0 ? 2048 : (grp == 1 ? 0 : 1024);
    bf16_t* dst = grp == 0 ? wvb : (grp == 1 ? wqb : wkb);
    const size_t idx = (size_t)tb * 2048 + (size_t)t * 8;   // idx = d*1024 + e
    const int d = (int)(idx >> 10);
    const int e = (int)(idx & 1023);
    const float* src = w_qkv + (size_t)d * 3072 + off + e;
    const float4 v0 = *(const float4*)src;
    const float4 v1 = *(const float4*)(src + 4);
    bf16x8 o;
    o[0] = (bf16_t)v0.x; o[1] = (bf16_t)v0.y; o[2] = (bf16_t)v0.z; o[3] = (bf16_t)v0.w;
    o[4] = (bf16_t)v1.x; o[5] = (bf16_t)v1.y; o[6] = (bf16_t)v1.z; o[7] = (bf16_t)v1.w;
    *(bf16x8*)(dst + idx) = o;
    return;
  }
  // w_out transpose
  const int tb = bxk - 4096;
  const int c0 = (tb & 31) * 32;
  const int r0 = (tb >> 5) * 32;
  const int tx = t & 31, ty = t >> 5;
#pragma unroll
  for (int rr = 0; rr < 32; rr += 8)
    tile[ty + rr][tx] = w_out[(size_t)(r0 + ty + rr) * 1024 + (c0 + tx)];
  __syncthreads();
#pragma unroll
  for (int cc = 0; cc < 32; cc += 8)
    wot[(size_t)(c0 + ty + cc) * 1024 + (r0 + tx)] = (bf16_t)tile[tx][ty + cc];
}

// ---------------- GEMM kernels ----------------

// WCOMB: two 1024x1024 weight-combine GEMMs, 128 blocks each.
// blocks [0,128):   wcombt[o,d] = sum_j wot[o,j]*wvb[d,j]  = (Wv@Wout)^T
// blocks [128,256): wqkt[d',d]  = sum_e wkb[d',e]*wqb[d,e] = (Wq@Wk^T)^T
// These let V and K never be materialized: X@(Wv@Wout) == (X@Wv)@Wout and
// sim == (X@(Wq Wk^T)) @ X^T.
__global__ void __launch_bounds__(256) k_wcomb(
    const bf16_t* __restrict__ wot, const bf16_t* __restrict__ wvb,
    const bf16_t* __restrict__ wqb, const bf16_t* __restrict__ wkb,
    bf16_t* __restrict__ wcombt, bf16_t* __restrict__ wqkt) {
  __shared__ bf16_t ldsA[64 * BK];
  __shared__ bf16_t ldsB[BN * BK];
  floatx4 acc[2][4];
  const int l = blockIdx.x;
  const bool second = l >= 128;
  const int ll = second ? (l - 128) : l;
  const bf16_t* A  = second ? wkb : wot;
  const bf16_t* Bt = second ? wqb : wvb;
  bf16_t* dst = second ? wqkt : wcombt;
  const int by = ll >> 3, bx = ll & 7;
  const int rowBase = by * 64, colBase = bx * BN;
  gemm_bt_core64(A, 1024, Bt, 1024, rowBase, colBase, 1024 / BK, ldsA, ldsB, acc);
  EPILOGUE_SETUP();
#pragma unroll
  for (int i = 0; i < 2; ++i) {
    const int m0 = rowBase + wy * 32 + i * 16 + quad * 4;
#pragma unroll
    for (int j = 0; j < 4; ++j) {
      const int n = colBase + wx * 64 + j * 16 + r16;
#pragma unroll
      for (int rr = 0; rr < 4; ++rr)
        dst[(size_t)(m0 + rr) * 1024 + n] = (bf16_t)acc[i][j][rr];
    }
  }
}

// QKV: C[8192,2048] = X @ [Wqk | Wcomb]^T. 2048 output cols = Y (pre-scaled
// 2^-5; feeds sim = Y@X^T) and VW (transposed VWt scatter). 256x128-tile,
// 512-thread (8 waves 4Mx2N each 64x64), BK=64, 3-deep LDS ring (144KB,
// 1 block/CU), prefetch distance 2 K-tiles, 2 phases/K-tile each
// {8 ds_read_b128 | 3 gld_lds -> barrier -> setprio(1) 16 MFMA setprio(0)
// -> barrier}, counted vmcnt(6) at K-tile boundary (never 0 mid-loop).
// Measured 820 TF active (R1). Grid 32x16 = 512 = exactly 2 CU rounds.
// XCD-aware: xcd owns 2 col-tiles (B slice 512KB, L2-resident).
#define BM2 256
#define BN2 128
__global__ void __launch_bounds__(512, 1) k_gemm_qkv(
    const bf16_t* __restrict__ X, const bf16_t* __restrict__ Wqkt,
    const bf16_t* __restrict__ Wct,
    bf16_t* __restrict__ Y, bf16_t* __restrict__ VWt) {
  __shared__ bf16_t lds[3][(BM2 + BN2) * BK];   // 147456 B
  const int l = blockIdx.x;
  const int xcd = l & 7;
  const int s = l >> 3;               // 0..63
  const int bx = xcd * 2 + (s & 1);   // 0..15
  const int by = s >> 1;              // 0..31
  const int rowBase = by * BM2;
  const int colBase = bx * BN2;
  const int region = colBase >> 10;   // 0=Y 1=VW (block-uniform)
  const bf16_t* Bt = region ? Wct : Wqkt;
  const int cb = colBase & 1023;

  const int t    = threadIdx.x;
  const int lane = t & 63;
  const int wave = t >> 6;          // 0..7
  const int wy   = wave >> 1;       // 0..3: 64-row band
  const int wx   = wave & 1;        // 0..1: 64-col half
  const int quad = lane >> 4;
  const int r16  = lane & 15;

  // staging: one issue = 512 lanes x 16B = 8KB = 64 rows of 128B
  const int srow   = t >> 3;                  // 0..63
  const int schunk = (t & 7) ^ (srow & 7);
  const bf16_t* ga = X  + (size_t)(rowBase + srow) * 1024 + schunk * 8;
  const bf16_t* gb = Bt + (size_t)(cb      + srow) * 1024 + schunk * 8;

  floatx4 acc[4][4];
#pragma unroll
  for (int i = 0; i < 4; ++i)
#pragma unroll
    for (int j = 0; j < 4; ++j)
      acc[i][j] = (floatx4){0.f, 0.f, 0.f, 0.f};

  const int nt = 1024 / BK;   // 16

  // prologue: stage tiles 0 and 1 (6 issues each: A rounds 0-3, B rounds 0-1)
#pragma unroll
  for (int r = 0; r < 4; ++r)
    gld_lds16(ga + (size_t)(64 * r) * 1024, &lds[0][(64 * r) * BK + t * 8]);
#pragma unroll
  for (int r = 0; r < 2; ++r)
    gld_lds16(gb + (size_t)(64 * r) * 1024, &lds[0][BM2 * BK + (64 * r) * BK + t * 8]);
#pragma unroll
  for (int r = 0; r < 4; ++r)
    gld_lds16(ga + BK + (size_t)(64 * r) * 1024, &lds[1][(64 * r) * BK + t * 8]);
#pragma unroll
  for (int r = 0; r < 2; ++r)
    gld_lds16(gb + BK + (size_t)(64 * r) * 1024, &lds[1][BM2 * BK + (64 * r) * BK + t * 8]);
  asm volatile("s_waitcnt vmcnt(6)" ::: "memory");   // tile 0 landed
  __builtin_amdgcn_s_barrier();
  asm volatile("" ::: "memory");

#define QKV_PHASE(H, STAGE_BODY)                                                   \
  {                                                                                \
    bf16x8 af[4], bfr[4];                                                          \
    _Pragma("unroll")                                                              \
    for (int i = 0; i < 4; ++i) {                                                  \
      const int r = wy * 64 + i * 16 + r16;                                        \
      af[i] = *(const bf16x8*)(la + r * BK + ((((H) << 2) + quad) ^ (r16 & 7)) * 8); \
    }                                                                              \
    _Pragma("unroll")                                                              \
    for (int j = 0; j < 4; ++j) {                                                  \
      const int r = wx * 64 + j * 16 + r16;                                        \
      bfr[j] = *(const bf16x8*)(lb + r * BK + ((((H) << 2) + quad) ^ (r16 & 7)) * 8); \
    }                                                                              \
    STAGE_BODY                                                                     \
    asm volatile("" ::: "memory");                                                 \
    __builtin_amdgcn_s_barrier();                                                  \
    __builtin_amdgcn_s_setprio(1);                                                 \
    _Pragma("unroll")                                                              \
    for (int i = 0; i < 4; ++i)                                                    \
      _Pragma("unroll")                                                            \
      for (int j = 0; j < 4; ++j)                                                  \
        acc[i][j] = __builtin_amdgcn_mfma_f32_16x16x32_bf16(af[i], bfr[j], acc[i][j], 0, 0, 0); \
    __builtin_amdgcn_s_setprio(0);                                                 \
  }

  for (int kt = 0; kt < nt; ++kt) {
    const int cur = kt % 3;
    const bf16_t* la = &lds[cur][0];
    const bf16_t* lb = &lds[cur][BM2 * BK];
    bf16_t* ldst = &lds[(kt + 2) % 3][0];
    const size_t k2 = (size_t)(kt + 2) * BK;
    const bool pf = (kt + 2) < nt;

    // phase 0: K-half 0 + stage A rounds 0-2 of tile kt+2
    QKV_PHASE(0, {
      if (pf) {
        gld_lds16(ga + k2,                        ldst + t * 8);
        gld_lds16(ga + k2 + (size_t)( 64) * 1024, ldst +  64 * BK + t * 8);
        gld_lds16(ga + k2 + (size_t)(128) * 1024, ldst + 128 * BK + t * 8);
      }
    });
    asm volatile("" ::: "memory");
    __builtin_amdgcn_s_barrier();           // phase boundary
    asm volatile("" ::: "memory");

    // phase 1: K-half 1 + stage A round 3, B rounds 0-1 of tile kt+2
    QKV_PHASE(1, {
      if (pf) {
        gld_lds16(ga + k2 + (size_t)(192) * 1024, ldst + 192 * BK + t * 8);
        gld_lds16(gb + k2,                        ldst + BM2 * BK + t * 8);
        gld_lds16(gb + k2 + (size_t)( 64) * 1024, ldst + BM2 * BK + 64 * BK + t * 8);
      }
    });
    if (kt + 1 < nt) {
      if (kt + 2 < nt) { asm volatile("s_waitcnt vmcnt(6)" ::: "memory"); }
      else             { asm volatile("s_waitcnt vmcnt(0)" ::: "memory"); }
      __builtin_amdgcn_s_barrier();         // tile kt+1 ready for all waves
      asm volatile("" ::: "memory");
    }
  }
#undef QKV_PHASE

  // epilogue
  if (region == 0) {
    const float scale = 0.03125f;   // fold softmax 1024^-0.5 into Y
#pragma unroll
    for (int i = 0; i < 4; ++i) {
      const int m0 = rowBase + wy * 64 + i * 16 + quad * 4;
#pragma unroll
      for (int j = 0; j < 4; ++j) {
        const int n = cb + wx * 64 + j * 16 + r16;
#pragma unroll
        for (int rr = 0; rr < 4; ++rr)
          Y[(size_t)(m0 + rr) * 1024 + n] = (bf16_t)(acc[i][j][rr] * scale);
      }
    }
  } else {
    // VWt[b][n][s] = (X @ Wcomb)^T, bf16 (transposed scatter along s)
    const int b = rowBase >> 11;              // 256-aligned rows: uniform batch
#pragma unroll
    for (int i = 0; i < 4; ++i) {
      const int m0 = rowBase + wy * 64 + i * 16 + quad * 4;
      const int s0 = m0 & 2047;
#pragma unroll
      for (int j = 0; j < 4; ++j) {
        const int n = cb + wx * 64 + j * 16 + r16;
        bf16x4 pk;
#pragma unroll
        for (int rr = 0; rr < 4; ++rr) pk[rr] = (bf16_t)acc[i][j][rr];
        *(bf16x4*)(VWt + (size_t)(b * 1024 + n) * 2048 + s0) = pk;
      }
    }
  }
}

// QKEXP: sim = Y @ X^T + exp, causal, 64x128 tiles. 272 tiles/batch x 4 =
// 1088 blocks. B operand is xb (K was never materialized: Y = X@(Wq Wk^T)).
// Triangular decode: tiles per row-block byp is (byp>>1)+1; prefix(2u)=u(u+1),
// prefix(2u+1)=(u+1)^2. Y pre-scaled so acc == logit (|logit| << 88, no max-sub).
__global__ void __launch_bounds__(256) k_qkexp(
    const bf16_t* __restrict__ Q, const bf16_t* __restrict__ Kmat,
    bf16_t* __restrict__ P, float* __restrict__ rowsum) {
  __shared__ bf16_t ldsA[64 * BK];
  __shared__ bf16_t ldsB[BN * BK];
  floatx4 acc[2][4];
  const int l = blockIdx.x;
  const int b = l / 272;
  const int lin = l - 272 * b;
  int r = (int)sqrtf((float)lin + 0.5f);
  while (r * r > lin) --r;
  while ((r + 1) * (r + 1) <= lin) ++r;
  int byp, bx;
  if (lin >= r * (r + 1)) { byp = 2 * r;     bx = lin - r * (r + 1); }
  else                    { byp = 2 * r - 1; bx = lin - r * r;       }
  const int rowBase = byp * 64, colBase = bx * BN;

  const bf16_t* Ab = Q    + (size_t)b * 2048 * 1024;
  const bf16_t* Bb = Kmat + (size_t)b * 2048 * 1024;
  gemm_bt_core64(Ab, 1024, Bb, 1024, rowBase, colBase, 1024 / BK, ldsA, ldsB, acc);

  bf16_t* Pb = P + (size_t)b * 2048 * 2048;
  float* rs = rowsum + (size_t)b * 2048;
  EPILOGUE_SETUP();
  const bool offdiag = (colBase + BN - 1 <= rowBase);   // whole tile unmasked

  float partial[2][4];
#pragma unroll
  for (int i = 0; i < 2; ++i)
#pragma unroll
    for (int rr = 0; rr < 4; ++rr) partial[i][rr] = 0.f;

#pragma unroll
  for (int i = 0; i < 2; ++i) {
    const int m0 = rowBase + wy * 32 + i * 16 + quad * 4;
#pragma unroll
    for (int j = 0; j < 4; ++j) {
      const int n = colBase + wx * 64 + j * 16 + r16;
#pragma unroll
      for (int rr = 0; rr < 4; ++rr) {
        const int m = m0 + rr;
        const float e = (offdiag || n <= m) ? __expf(acc[i][j][rr]) : 0.0f;
        Pb[(size_t)m * 2048 + n] = (bf16_t)e;
        partial[i][rr] += e;
      }
    }
  }
#pragma unroll
  for (int i = 0; i < 2; ++i)
#pragma unroll
    for (int rr = 0; rr < 4; ++rr) {
      float v = partial[i][rr];
      v += __shfl_xor(v, 1, 64);
      v += __shfl_xor(v, 2, 64);
      v += __shfl_xor(v, 4, 64);
      v += __shfl_xor(v, 8, 64);
      partial[i][rr] = v;
    }
  if (r16 == 0) {
#pragma unroll
    for (int i = 0; i < 2; ++i) {
      const int m0 = rowBase + wy * 32 + i * 16 + quad * 4;
#pragma unroll
      for (int rr = 0; rr < 4; ++rr)
        atomicAdd(&rs[m0 + rr], partial[i][rr]);
    }
  }
}

// POVW: out[b][m][n] = (P_unnorm @ VWt^T) * inv_rowsum + bias, fp32.
// 64x128 tiles: 1024 blocks = 4/CU. Causal bound at 64-row granularity:
// ktiles = by'+1. Per-CU balance: blocks l, l+256, l+512, l+768 get
// by' = {31-w, w, 16+w, 15-w} -> 66 ktiles per CU, constant.
__global__ void __launch_bounds__(256) k_gemm_povw(
    const bf16_t* __restrict__ P, const bf16_t* __restrict__ VWt,
    const float* __restrict__ rowsum, const float* __restrict__ bias,
    float* __restrict__ out) {
  const int l = blockIdx.x;
  const int z = l >> 8;
  const int idx = l & 255;
  const int bx = idx & 7;
  const int w = (idx >> 3) & 7;
  const int b = idx >> 6;
  const int byp = (z == 0) ? (31 - w) : (z == 1) ? w : (z == 2) ? (16 + w) : (15 - w);

  __shared__ bf16_t ldsA[64 * BK];
  __shared__ bf16_t ldsB[BN * BK];
  floatx4 acc[2][4];
  const bf16_t* Ab = P + (size_t)b * 2048 * 2048;
  const bf16_t* Bb = VWt + (size_t)b * 1024 * 2048;
  const int rowBase = byp * 64, colBase = bx * BN;
  gemm_bt_core64(Ab, 2048, Bb, 2048, rowBase, colBase, byp + 1, ldsA, ldsB, acc);
  const float* rs = rowsum + (size_t)b * 2048;
  EPILOGUE_SETUP();
#pragma unroll
  for (int i = 0; i < 2; ++i) {
    const int m0 = rowBase + wy * 32 + i * 16 + quad * 4;
#pragma unroll
    for (int rr = 0; rr < 4; ++rr) {
      const float inv = 1.0f / rs[m0 + rr];
      const size_t row = (size_t)b * 2048 + m0 + rr;
#pragma unroll
      for (int j = 0; j < 4; ++j) {
        const int n = colBase + wx * 64 + j * 16 + r16;
        out[row * 1024 + n] = acc[i][j][rr] * inv + bias[n];
      }
    }
  }
}

// ---------------- launch ----------------
// ws layout (bytes):
//   xb     @ 0          16,777,216   x as bf16 [8192,1024]
//   woutt  @ 23068672    2,097,152   w_out^T bf16 [1024,1024]
//   y      @ 25165824   16,777,216   Y = X@(WqWk^T) bf16, pre-scaled 2^-5
//   wqb    @ 41943040    2,097,152   Wq = w_qkv[:,0:1024] bf16 row-major
//   wkb    @ 44040192    2,097,152   Wk = w_qkv[:,1024:2048] bf16 row-major
//   wqkt   @ 46137344    2,097,152   (Wq@Wk^T)^T bf16 [1024,1024]
//   wvb    @ 58720256    2,097,152   Wv = w_qkv[:,2048:3072] bf16 row-major
//   wcombt @ 60817408    2,097,152   (Wv@Wout)^T bf16 [1024,1024]
//   rowsum @ 75497472       32,768   [b,s] fp32 sum of exp
//   p      @ 142606336  33,554,432   [b,s,s] bf16 unnormalized exp(logit)
//   vwt    @ 176160768  16,777,216   [b,1024(n),s] bf16 (X@Wcomb transposed)
extern "C" void kernel_launch(void* const* d_in, const int* in_sizes, int n_in,
                              void* d_out, int out_size, void* d_ws, size_t ws_size,
                              hipStream_t stream) {
  const float* x     = (const float*)d_in[0];
  const float* w_qkv = (const float*)d_in[1];
  const float* w_out = (const float*)d_in[2];
  const float* b_out = (const float*)d_in[3];
  float* out = (float*)d_out;
  char* ws = (char*)d_ws;

  bf16_t* xb     = (bf16_t*)(ws + 0);
  bf16_t* wot    = (bf16_t*)(ws + 23068672);
  bf16_t* y      = (bf16_t*)(ws + 25165824);
  bf16_t* wqb    = (bf16_t*)(ws + 41943040);
  bf16_t* wkb    = (bf16_t*)(ws + 44040192);
  bf16_t* wqkt   = (bf16_t*)(ws + 46137344);
  bf16_t* wvb    = (bf16_t*)(ws + 58720256);
  bf16_t* wcombt = (bf16_t*)(ws + 60817408);
  float*  rowsum = (float*)(ws + 75497472);
  bf16_t* p      = (bf16_t*)(ws + 142606336);
  bf16_t* vwt    = (bf16_t*)(ws + 176160768);

  k_prep<<<6656, 256, 0, stream>>>(x, xb, w_qkv, w_out, wot, rowsum, wvb, wqb, wkb);
  k_wcomb<<<256, 256, 0, stream>>>(wot, wvb, wqb, wkb, wcombt, wqkt);
  k_gemm_qkv<<<512, 512, 0, stream>>>(xb, wqkt, wcombt, y, vwt);
  k_qkexp<<<1088, 256, 0, stream>>>(y, xb, p, rowsum);
  k_gemm_povw<<<1024, 256, 0, stream>>>(p, vwt, rowsum, b_out, out);
}

// Round 6
// 213.624 us; speedup vs baseline: 1.2371x; 1.0524x over previous
//
#include <hip/hip_runtime.h>

typedef __bf16 bf16_t;
typedef __bf16 bf16x8 __attribute__((ext_vector_type(8)));
typedef __bf16 bf16x4 __attribute__((ext_vector_type(4)));
typedef float  floatx4 __attribute__((ext_vector_type(4)));

#define BM 128
#define BN 128
#define BK 64

// async global->LDS, 16B per lane. LDS dest is wave-uniform base + lane*16 (no
// scatter, no padding) — conflict-avoidance is done by permuting the GLOBAL
// chunk each lane fetches (XOR swizzle), not the LDS address.
__device__ __forceinline__ void gld_lds16(const bf16_t* g, bf16_t* l) {
  __builtin_amdgcn_global_load_lds(
      (__attribute__((address_space(1))) const void*)g,
      (__attribute__((address_space(3))) void*)l, 16, 0, 0);
}

// 64x128 variant: BM=64, BN=128, waves 2x2 each 32x64, acc[2][4].
// LDS row-major [rows][BK=64]; chunk s of row r holds global chunk s^(r&7).
__device__ __forceinline__ void gemm_bt_core64(
    const bf16_t* __restrict__ A, int lda,
    const bf16_t* __restrict__ Bt, int ldb,
    int rowBase, int colBase, int kTiles,
    bf16_t* ldsA, bf16_t* ldsB, floatx4 acc[2][4])
{
  const int t    = threadIdx.x;
  const int lane = t & 63;
  const int wave = t >> 6;
  const int wy   = wave >> 1;      // 32-row half
  const int wx   = wave & 1;       // 64-col half
  const int quad = lane >> 4;
  const int r16  = lane & 15;

  const int srow   = t >> 3;
  const int schunk = (t & 7) ^ (srow & 7);
  const bf16_t* ga = A  + (size_t)(rowBase + srow) * lda + schunk * 8;
  const bf16_t* gb = Bt + (size_t)(colBase + srow) * ldb + schunk * 8;
  bf16_t* la = ldsA + t * 8;
  bf16_t* lb = ldsB + t * 8;

#pragma unroll
  for (int i = 0; i < 2; ++i)
#pragma unroll
    for (int j = 0; j < 4; ++j)
      acc[i][j] = (floatx4){0.f, 0.f, 0.f, 0.f};

  for (int kt = 0; kt < kTiles; ++kt) {
    const int k0 = kt * BK;
    gld_lds16(ga + k0,                    la);             // A: 64 rows = 2 issues
    gld_lds16(ga + k0 + (size_t)32 * lda, la + 32 * BK);
#pragma unroll
    for (int is = 0; is < 4; ++is)                         // B: 128 rows = 4 issues
      gld_lds16(gb + k0 + (size_t)(32 * is) * ldb, lb + is * (32 * BK));
    __syncthreads();

#pragma unroll
    for (int h = 0; h < 2; ++h) {
      bf16x8 af[2], bfr[4];
#pragma unroll
      for (int i = 0; i < 2; ++i) {
        const int r = wy * 32 + i * 16 + r16;
        af[i] = *(const bf16x8*)(ldsA + r * BK + (((h << 2) + quad) ^ (r16 & 7)) * 8);
      }
#pragma unroll
      for (int j = 0; j < 4; ++j) {
        const int r = wx * 64 + j * 16 + r16;
        bfr[j] = *(const bf16x8*)(ldsB + r * BK + (((h << 2) + quad) ^ (r16 & 7)) * 8);
      }
#pragma unroll
      for (int i = 0; i < 2; ++i)
#pragma unroll
        for (int j = 0; j < 4; ++j)
          acc[i][j] = __builtin_amdgcn_mfma_f32_16x16x32_bf16(af[i], bfr[j], acc[i][j], 0, 0, 0);
    }
    __syncthreads();
  }
}

#define EPILOGUE_SETUP()                       \
  const int t    = threadIdx.x;                \
  const int lane = t & 63;                     \
  const int wave = t >> 6;                     \
  const int wy   = wave >> 1;                  \
  const int wx   = wave & 1;                   \
  const int quad = lane >> 4;                  \
  const int r16  = lane & 15;

// ---------------- fused prep kernel ----------------
// blocks [0,4096): x fp32 -> bf16, 8 elems/thread; blocks [0,32) also zero rowsum
// blocks [4096,5120): transpose+cvt w_out [1024,1024] -> wot [1024,1024]
// blocks [5120,6656): strided cvt of w_qkv column slices (row-major, no transpose):
//   grp 0: wvb = w_qkv[:,2048:3072]  grp 1: wqb = w_qkv[:,0:1024]
//   grp 2: wkb = w_qkv[:,1024:2048]
// The w_qkv transpose is GONE: Q/K GEMMs are folded into Wqk = Wq@Wk^T
// (sim = X (Wq Wk^T) X^T), so only row-major weight slices are needed.
__global__ void __launch_bounds__(256) k_prep(
    const float* __restrict__ x, bf16_t* __restrict__ xb,
    const float* __restrict__ w_qkv, const float* __restrict__ w_out,
    bf16_t* __restrict__ wot, float* __restrict__ rowsum,
    bf16_t* __restrict__ wvb, bf16_t* __restrict__ wqb, bf16_t* __restrict__ wkb) {
  __shared__ float tile[32][33];
  const int bxk = blockIdx.x;
  const int t = threadIdx.x;
  if (bxk < 4096) {
    const size_t idx = (size_t)bxk * 256 + t;
    if (bxk < 32) rowsum[idx] = 0.0f;
    const float4 v0 = ((const float4*)x)[idx * 2];
    const float4 v1 = ((const float4*)x)[idx * 2 + 1];
    bf16x8 o;
    o[0] = (bf16_t)v0.x; o[1] = (bf16_t)v0.y; o[2] = (bf16_t)v0.z; o[3] = (bf16_t)v0.w;
    o[4] = (bf16_t)v1.x; o[5] = (bf16_t)v1.y; o[6] = (bf16_t)v1.z; o[7] = (bf16_t)v1.w;
    ((bf16x8*)xb)[idx] = o;
    return;
  }
  if (bxk >= 5120) {
    const int ridx = bxk - 5120;
    const int grp = ridx >> 9;          // 0,1,2
    const int tb  = ridx & 511;
    const int off = grp == 0 ? 2048 : (grp == 1 ? 0 : 1024);
    bf16_t* dst = grp == 0 ? wvb : (grp == 1 ? wqb : wkb);
    const size_t idx = (size_t)tb * 2048 + (size_t)t * 8;   // idx = d*1024 + e
    const int d = (int)(idx >> 10);
    const int e = (int)(idx & 1023);
    const float* src = w_qkv + (size_t)d * 3072 + off + e;
    const float4 v0 = *(const float4*)src;
    const float4 v1 = *(const float4*)(src + 4);
    bf16x8 o;
    o[0] = (bf16_t)v0.x; o[1] = (bf16_t)v0.y; o[2] = (bf16_t)v0.z; o[3] = (bf16_t)v0.w;
    o[4] = (bf16_t)v1.x; o[5] = (bf16_t)v1.y; o[6] = (bf16_t)v1.z; o[7] = (bf16_t)v1.w;
    *(bf16x8*)(dst + idx) = o;
    return;
  }
  // w_out transpose
  const int tb = bxk - 4096;
  const int c0 = (tb & 31) * 32;
  const int r0 = (tb >> 5) * 32;
  const int tx = t & 31, ty = t >> 5;
#pragma unroll
  for (int rr = 0; rr < 32; rr += 8)
    tile[ty + rr][tx] = w_out[(size_t)(r0 + ty + rr) * 1024 + (c0 + tx)];
  __syncthreads();
#pragma unroll
  for (int cc = 0; cc < 32; cc += 8)
    wot[(size_t)(c0 + ty + cc) * 1024 + (r0 + tx)] = (bf16_t)tile[tx][ty + cc];
}

// ---------------- GEMM kernels ----------------

// WCOMB: two 1024x1024 weight-combine GEMMs, 128 blocks each.
// blocks [0,128):   wcombt[o,d] = sum_j wot[o,j]*wvb[d,j]  = (Wv@Wout)^T
// blocks [128,256): wqkt[d',d]  = sum_e wkb[d',e]*wqb[d,e] = (Wq@Wk^T)^T
// These let V and K never be materialized: X@(Wv@Wout) == (X@Wv)@Wout and
// sim == (X@(Wq Wk^T)) @ X^T.
__global__ void __launch_bounds__(256) k_wcomb(
    const bf16_t* __restrict__ wot, const bf16_t* __restrict__ wvb,
    const bf16_t* __restrict__ wqb, const bf16_t* __restrict__ wkb,
    bf16_t* __restrict__ wcombt, bf16_t* __restrict__ wqkt) {
  __shared__ bf16_t ldsA[64 * BK];
  __shared__ bf16_t ldsB[BN * BK];
  floatx4 acc[2][4];
  const int l = blockIdx.x;
  const bool second = l >= 128;
  const int ll = second ? (l - 128) : l;
  const bf16_t* A  = second ? wkb : wot;
  const bf16_t* Bt = second ? wqb : wvb;
  bf16_t* dst = second ? wqkt : wcombt;
  const int by = ll >> 3, bx = ll & 7;
  const int rowBase = by * 64, colBase = bx * BN;
  gemm_bt_core64(A, 1024, Bt, 1024, rowBase, colBase, 1024 / BK, ldsA, ldsB, acc);
  EPILOGUE_SETUP();
#pragma unroll
  for (int i = 0; i < 2; ++i) {
    const int m0 = rowBase + wy * 32 + i * 16 + quad * 4;
#pragma unroll
    for (int j = 0; j < 4; ++j) {
      const int n = colBase + wx * 64 + j * 16 + r16;
#pragma unroll
      for (int rr = 0; rr < 4; ++rr)
        dst[(size_t)(m0 + rr) * 1024 + n] = (bf16_t)acc[i][j][rr];
    }
  }
}

// QKV: C[8192,2048] = X @ [Wqk | Wcomb]^T. 2048 output cols = Y (pre-scaled
// 2^-5; feeds sim = Y@X^T) and VW (transposed VWt scatter). 256x128-tile,
// 512-thread (8 waves 4Mx2N each 64x64), BK=64, 3-deep LDS ring (144KB,
// 1 block/CU), prefetch distance 2 K-tiles, 2 phases/K-tile each
// {8 ds_read_b128 | 3 gld_lds -> barrier -> setprio(1) 16 MFMA setprio(0)
// -> barrier}, counted vmcnt(6) at K-tile boundary (never 0 mid-loop).
// Measured 764-820 TF active (R1/R4). Grid 32x16 = 512 = exactly 2 CU rounds.
// XCD-aware: xcd owns 2 col-tiles (B slice 512KB, L2-resident).
#define BM2 256
#define BN2 128
__global__ void __launch_bounds__(512, 1) k_gemm_qkv(
    const bf16_t* __restrict__ X, const bf16_t* __restrict__ Wqkt,
    const bf16_t* __restrict__ Wct,
    bf16_t* __restrict__ Y, bf16_t* __restrict__ VWt) {
  __shared__ bf16_t lds[3][(BM2 + BN2) * BK];   // 147456 B
  const int l = blockIdx.x;
  const int xcd = l & 7;
  const int s = l >> 3;               // 0..63
  const int bx = xcd * 2 + (s & 1);   // 0..15
  const int by = s >> 1;              // 0..31
  const int rowBase = by * BM2;
  const int colBase = bx * BN2;
  const int region = colBase >> 10;   // 0=Y 1=VW (block-uniform)
  const bf16_t* Bt = region ? Wct : Wqkt;
  const int cb = colBase & 1023;

  const int t    = threadIdx.x;
  const int lane = t & 63;
  const int wave = t >> 6;          // 0..7
  const int wy   = wave >> 1;       // 0..3: 64-row band
  const int wx   = wave & 1;        // 0..1: 64-col half
  const int quad = lane >> 4;
  const int r16  = lane & 15;

  // staging: one issue = 512 lanes x 16B = 8KB = 64 rows of 128B
  const int srow   = t >> 3;                  // 0..63
  const int schunk = (t & 7) ^ (srow & 7);
  const bf16_t* ga = X  + (size_t)(rowBase + srow) * 1024 + schunk * 8;
  const bf16_t* gb = Bt + (size_t)(cb      + srow) * 1024 + schunk * 8;

  floatx4 acc[4][4];
#pragma unroll
  for (int i = 0; i < 4; ++i)
#pragma unroll
    for (int j = 0; j < 4; ++j)
      acc[i][j] = (floatx4){0.f, 0.f, 0.f, 0.f};

  const int nt = 1024 / BK;   // 16

  // prologue: stage tiles 0 and 1 (6 issues each: A rounds 0-3, B rounds 0-1)
#pragma unroll
  for (int r = 0; r < 4; ++r)
    gld_lds16(ga + (size_t)(64 * r) * 1024, &lds[0][(64 * r) * BK + t * 8]);
#pragma unroll
  for (int r = 0; r < 2; ++r)
    gld_lds16(gb + (size_t)(64 * r) * 1024, &lds[0][BM2 * BK + (64 * r) * BK + t * 8]);
#pragma unroll
  for (int r = 0; r < 4; ++r)
    gld_lds16(ga + BK + (size_t)(64 * r) * 1024, &lds[1][(64 * r) * BK + t * 8]);
#pragma unroll
  for (int r = 0; r < 2; ++r)
    gld_lds16(gb + BK + (size_t)(64 * r) * 1024, &lds[1][BM2 * BK + (64 * r) * BK + t * 8]);
  asm volatile("s_waitcnt vmcnt(6)" ::: "memory");   // tile 0 landed
  __builtin_amdgcn_s_barrier();
  asm volatile("" ::: "memory");

#define QKV_PHASE(H, STAGE_BODY)                                                   \
  {                                                                                \
    bf16x8 af[4], bfr[4];                                                          \
    _Pragma("unroll")                                                              \
    for (int i = 0; i < 4; ++i) {                                                  \
      const int r = wy * 64 + i * 16 + r16;                                        \
      af[i] = *(const bf16x8*)(la + r * BK + ((((H) << 2) + quad) ^ (r16 & 7)) * 8); \
    }                                                                              \
    _Pragma("unroll")                                                              \
    for (int j = 0; j < 4; ++j) {                                                  \
      const int r = wx * 64 + j * 16 + r16;                                        \
      bfr[j] = *(const bf16x8*)(lb + r * BK + ((((H) << 2) + quad) ^ (r16 & 7)) * 8); \
    }                                                                              \
    STAGE_BODY                                                                     \
    asm volatile("" ::: "memory");                                                 \
    __builtin_amdgcn_s_barrier();                                                  \
    __builtin_amdgcn_s_setprio(1);                                                 \
    _Pragma("unroll")                                                              \
    for (int i = 0; i < 4; ++i)                                                    \
      _Pragma("unroll")                                                            \
      for (int j = 0; j < 4; ++j)                                                  \
        acc[i][j] = __builtin_amdgcn_mfma_f32_16x16x32_bf16(af[i], bfr[j], acc[i][j], 0, 0, 0); \
    __builtin_amdgcn_s_setprio(0);                                                 \
  }

  for (int kt = 0; kt < nt; ++kt) {
    const int cur = kt % 3;
    const bf16_t* la = &lds[cur][0];
    const bf16_t* lb = &lds[cur][BM2 * BK];
    bf16_t* ldst = &lds[(kt + 2) % 3][0];
    const size_t k2 = (size_t)(kt + 2) * BK;
    const bool pf = (kt + 2) < nt;

    // phase 0: K-half 0 + stage A rounds 0-2 of tile kt+2
    QKV_PHASE(0, {
      if (pf) {
        gld_lds16(ga + k2,                        ldst + t * 8);
        gld_lds16(ga + k2 + (size_t)( 64) * 1024, ldst +  64 * BK + t * 8);
        gld_lds16(ga + k2 + (size_t)(128) * 1024, ldst + 128 * BK + t * 8);
      }
    });
    asm volatile("" ::: "memory");
    __builtin_amdgcn_s_barrier();           // phase boundary
    asm volatile("" ::: "memory");

    // phase 1: K-half 1 + stage A round 3, B rounds 0-1 of tile kt+2
    QKV_PHASE(1, {
      if (pf) {
        gld_lds16(ga + k2 + (size_t)(192) * 1024, ldst + 192 * BK + t * 8);
        gld_lds16(gb + k2,                        ldst + BM2 * BK + t * 8);
        gld_lds16(gb + k2 + (size_t)( 64) * 1024, ldst + BM2 * BK + 64 * BK + t * 8);
      }
    });
    if (kt + 1 < nt) {
      if (kt + 2 < nt) { asm volatile("s_waitcnt vmcnt(6)" ::: "memory"); }
      else             { asm volatile("s_waitcnt vmcnt(0)" ::: "memory"); }
      __builtin_amdgcn_s_barrier();         // tile kt+1 ready for all waves
      asm volatile("" ::: "memory");
    }
  }
#undef QKV_PHASE

  // epilogue
  if (region == 0) {
    const float scale = 0.03125f;   // fold softmax 1024^-0.5 into Y
#pragma unroll
    for (int i = 0; i < 4; ++i) {
      const int m0 = rowBase + wy * 64 + i * 16 + quad * 4;
#pragma unroll
      for (int j = 0; j < 4; ++j) {
        const int n = cb + wx * 64 + j * 16 + r16;
#pragma unroll
        for (int rr = 0; rr < 4; ++rr)
          Y[(size_t)(m0 + rr) * 1024 + n] = (bf16_t)(acc[i][j][rr] * scale);
      }
    }
  } else {
    // VWt[b][n][s] = (X @ Wcomb)^T, bf16 (transposed scatter along s)
    const int b = rowBase >> 11;              // 256-aligned rows: uniform batch
#pragma unroll
    for (int i = 0; i < 4; ++i) {
      const int m0 = rowBase + wy * 64 + i * 16 + quad * 4;
      const int s0 = m0 & 2047;
#pragma unroll
      for (int j = 0; j < 4; ++j) {
        const int n = cb + wx * 64 + j * 16 + r16;
        bf16x4 pk;
#pragma unroll
        for (int rr = 0; rr < 4; ++rr) pk[rr] = (bf16_t)acc[i][j][rr];
        *(bf16x4*)(VWt + (size_t)(b * 1024 + n) * 2048 + s0) = pk;
      }
    }
  }
}

// QKEXP: sim = Y @ X^T + exp, causal, 64x128 tiles, 1088 blocks.
// XCD-pinned col-blocks for B-operand L2 containment: tile (byp,bx) exists for
// byp >= 2bx (count 32-2bx); pairing bx with 15-bx gives (32-2bx)+(2bx+2) = 34
// tiles/batch per XCD — perfectly balanced AND each XCD re-reads only 2 X
// col-bands (2MB over 4 batches, resident in its private 4MB L2). This
// replaces the R5 linear triangular decode whose bx striping forced every
// XCD to pull the whole 16.8MB X through L3 (the R4->R5 +15us anomaly).
// Y pre-scaled so acc == logit (|logit| << 88, no max-sub).
__global__ void __launch_bounds__(256) k_qkexp(
    const bf16_t* __restrict__ Q, const bf16_t* __restrict__ Kmat,
    bf16_t* __restrict__ P, float* __restrict__ rowsum) {
  __shared__ bf16_t ldsA[64 * BK];
  __shared__ bf16_t ldsB[BN * BK];
  floatx4 acc[2][4];
  const int l = blockIdx.x;
  const int xcd = l & 7;
  const int idx = l >> 3;          // 0..135
  const int b = idx / 34;
  const int r = idx - 34 * b;
  const int c1 = 32 - 2 * xcd;     // tiles with bx = xcd
  int bx, byp;
  if (r < c1) { bx = xcd;      byp = 2 * xcd + r; }
  else        { bx = 15 - xcd; byp = 2 * (15 - xcd) + (r - c1); }
  const int rowBase = byp * 64, colBase = bx * BN;

  const bf16_t* Ab = Q    + (size_t)b * 2048 * 1024;
  const bf16_t* Bb = Kmat + (size_t)b * 2048 * 1024;
  gemm_bt_core64(Ab, 1024, Bb, 1024, rowBase, colBase, 1024 / BK, ldsA, ldsB, acc);

  bf16_t* Pb = P + (size_t)b * 2048 * 2048;
  float* rs = rowsum + (size_t)b * 2048;
  EPILOGUE_SETUP();
  const bool offdiag = (colBase + BN - 1 <= rowBase);   // whole tile unmasked

  float partial[2][4];
#pragma unroll
  for (int i = 0; i < 2; ++i)
#pragma unroll
    for (int rr = 0; rr < 4; ++rr) partial[i][rr] = 0.f;

#pragma unroll
  for (int i = 0; i < 2; ++i) {
    const int m0 = rowBase + wy * 32 + i * 16 + quad * 4;
#pragma unroll
    for (int j = 0; j < 4; ++j) {
      const int n = colBase + wx * 64 + j * 16 + r16;
#pragma unroll
      for (int rr = 0; rr < 4; ++rr) {
        const int m = m0 + rr;
        const float e = (offdiag || n <= m) ? __expf(acc[i][j][rr]) : 0.0f;
        Pb[(size_t)m * 2048 + n] = (bf16_t)e;
        partial[i][rr] += e;
      }
    }
  }
#pragma unroll
  for (int i = 0; i < 2; ++i)
#pragma unroll
    for (int rr = 0; rr < 4; ++rr) {
      float v = partial[i][rr];
      v += __shfl_xor(v, 1, 64);
      v += __shfl_xor(v, 2, 64);
      v += __shfl_xor(v, 4, 64);
      v += __shfl_xor(v, 8, 64);
      partial[i][rr] = v;
    }
  if (r16 == 0) {
#pragma unroll
    for (int i = 0; i < 2; ++i) {
      const int m0 = rowBase + wy * 32 + i * 16 + quad * 4;
#pragma unroll
      for (int rr = 0; rr < 4; ++rr)
        atomicAdd(&rs[m0 + rr], partial[i][rr]);
    }
  }
}

// POVW: out[b][m][n] = (P_unnorm @ VWt^T) * inv_rowsum + bias, fp32.
// 64x128 tiles: 1024 blocks = 4/CU. Causal bound at 64-row granularity:
// ktiles = by'+1. Per-CU balance: blocks l, l+256, l+512, l+768 get
// by' = {31-w, w, 16+w, 15-w} -> 66 ktiles per CU, constant. bx = l&7 =
// XCD already pins each XCD to one VWt col-band (2MB/L2) by construction.
__global__ void __launch_bounds__(256) k_gemm_povw(
    const bf16_t* __restrict__ P, const bf16_t* __restrict__ VWt,
    const float* __restrict__ rowsum, const float* __restrict__ bias,
    float* __restrict__ out) {
  const int l = blockIdx.x;
  const int z = l >> 8;
  const int idx = l & 255;
  const int bx = idx & 7;
  const int w = (idx >> 3) & 7;
  const int b = idx >> 6;
  const int byp = (z == 0) ? (31 - w) : (z == 1) ? w : (z == 2) ? (16 + w) : (15 - w);

  __shared__ bf16_t ldsA[64 * BK];
  __shared__ bf16_t ldsB[BN * BK];
  floatx4 acc[2][4];
  const bf16_t* Ab = P + (size_t)b * 2048 * 2048;
  const bf16_t* Bb = VWt + (size_t)b * 1024 * 2048;
  const int rowBase = byp * 64, colBase = bx * BN;
  gemm_bt_core64(Ab, 2048, Bb, 2048, rowBase, colBase, byp + 1, ldsA, ldsB, acc);
  const float* rs = rowsum + (size_t)b * 2048;
  EPILOGUE_SETUP();
#pragma unroll
  for (int i = 0; i < 2; ++i) {
    const int m0 = rowBase + wy * 32 + i * 16 + quad * 4;
#pragma unroll
    for (int rr = 0; rr < 4; ++rr) {
      const float inv = 1.0f / rs[m0 + rr];
      const size_t row = (size_t)b * 2048 + m0 + rr;
#pragma unroll
      for (int j = 0; j < 4; ++j) {
        const int n = colBase + wx * 64 + j * 16 + r16;
        out[row * 1024 + n] = acc[i][j][rr] * inv + bias[n];
      }
    }
  }
}

// ---------------- launch ----------------
// ws layout (bytes):
//   xb     @ 0          16,777,216   x as bf16 [8192,1024]
//   woutt  @ 23068672    2,097,152   w_out^T bf16 [1024,1024]
//   y      @ 25165824   16,777,216   Y = X@(WqWk^T) bf16, pre-scaled 2^-5
//   wqb    @ 41943040    2,097,152   Wq = w_qkv[:,0:1024] bf16 row-major
//   wkb    @ 44040192    2,097,152   Wk = w_qkv[:,1024:2048] bf16 row-major
//   wqkt   @ 46137344    2,097,152   (Wq@Wk^T)^T bf16 [1024,1024]
//   wvb    @ 58720256    2,097,152   Wv = w_qkv[:,2048:3072] bf16 row-major
//   wcombt @ 60817408    2,097,152   (Wv@Wout)^T bf16 [1024,1024]
//   rowsum @ 75497472       32,768   [b,s] fp32 sum of exp
//   p      @ 142606336  33,554,432   [b,s,s] bf16 unnormalized exp(logit)
//   vwt    @ 176160768  16,777,216   [b,1024(n),s] bf16 (X@Wcomb transposed)
extern "C" void kernel_launch(void* const* d_in, const int* in_sizes, int n_in,
                              void* d_out, int out_size, void* d_ws, size_t ws_size,
                              hipStream_t stream) {
  const float* x     = (const float*)d_in[0];
  const float* w_qkv = (const float*)d_in[1];
  const float* w_out = (const float*)d_in[2];
  const float* b_out = (const float*)d_in[3];
  float* out = (float*)d_out;
  char* ws = (char*)d_ws;

  bf16_t* xb     = (bf16_t*)(ws + 0);
  bf16_t* wot    = (bf16_t*)(ws + 23068672);
  bf16_t* y      = (bf16_t*)(ws + 25165824);
  bf16_t* wqb    = (bf16_t*)(ws + 41943040);
  bf16_t* wkb    = (bf16_t*)(ws + 44040192);
  bf16_t* wqkt   = (bf16_t*)(ws + 46137344);
  bf16_t* wvb    = (bf16_t*)(ws + 58720256);
  bf16_t* wcombt = (bf16_t*)(ws + 60817408);
  float*  rowsum = (float*)(ws + 75497472);
  bf16_t* p      = (bf16_t*)(ws + 142606336);
  bf16_t* vwt    = (bf16_t*)(ws + 176160768);

  k_prep<<<6656, 256, 0, stream>>>(x, xb, w_qkv, w_out, wot, rowsum, wvb, wqb, wkb);
  k_wcomb<<<256, 256, 0, stream>>>(wot, wvb, wqb, wkb, wcombt, wqkt);
  k_gemm_qkv<<<512, 512, 0, stream>>>(xb, wqkt, wcombt, y, vwt);
  k_qkexp<<<1088, 256, 0, stream>>>(y, xb, p, rowsum);
  k_gemm_povw<<<1024, 256, 0, stream>>>(p, vwt, rowsum, b_out, out);
}